// Round 2
// baseline (4491.955 us; speedup 1.0000x reference)
//
#include <hip/hip_runtime.h>
#include <hip/hip_bf16.h>

// Problem constants
#define B_   4096
#define T_   60
#define TT   30          // pooled sequence length
#define H_   512
#define L_   2
#define NH_  4
#define DH_  128
#define LAT_ 128
#define OUT_ 14
#define NGATE_ (5*H_)    // 2560
#define EPSF 1e-5f
#define KVCHUNK 512      // batch rows per kv chunk (8 chunks)

typedef __attribute__((ext_vector_type(8))) short bf16x8;
typedef __attribute__((ext_vector_type(4))) float f32x4;

__device__ __forceinline__ float sigmoidf_(float x) { return 1.0f / (1.0f + __expf(-x)); }

__device__ __forceinline__ void async_load16(const void* g, void* l) {
    __builtin_amdgcn_global_load_lds((const __attribute__((address_space(1))) void*)g,
                                     (__attribute__((address_space(3))) void*)l, 16, 0, 0);
}

// ---------------------------------------------------------------------------
// Utility kernels
// ---------------------------------------------------------------------------
__global__ __launch_bounds__(256) void cvt_bf16(const float* __restrict__ in,
                                                __hip_bfloat16* __restrict__ out, long n) {
    long i = (long)blockIdx.x * blockDim.x + threadIdx.x;
    long stride = (long)gridDim.x * blockDim.x;
    for (; i < n; i += stride) out[i] = __float2bfloat16(in[i]);
}

__global__ __launch_bounds__(256) void zero_f32(float* __restrict__ p, long n) {
    long i = (long)blockIdx.x * blockDim.x + threadIdx.x;
    long stride = (long)gridDim.x * blockDim.x;
    for (; i < n; i += stride) p[i] = 0.0f;
}

// ---------------------------------------------------------------------------
// Front-end: conv1d(9->24,k3,p1)+relu+bn -> maxpool2 -> concat comp(8->20 relu)
//            -> proj (44->512) ; one block per batch row, 256 threads
// ---------------------------------------------------------------------------
__global__ __launch_bounds__(256)
void frontend_kernel(const float* __restrict__ x,
                     const float* __restrict__ cw, const float* __restrict__ cb,
                     const float* __restrict__ bg, const float* __restrict__ bb,
                     const float* __restrict__ brm, const float* __restrict__ brv,
                     const float* __restrict__ compw, const float* __restrict__ compb,
                     const float* __restrict__ pw, const float* __restrict__ pb,
                     __hip_bfloat16* __restrict__ combined) {
    const int b = blockIdx.x, tid = threadIdx.x;
    __shared__ float xs[T_ * 17];        // 4080 B
    __shared__ float ybuf[24][T_];       // 5760 B
    __shared__ float feat[TT][44];       // 5280 B

    for (int i = tid; i < T_ * 17; i += 256) xs[i] = x[(long)b * T_ * 17 + i];
    __syncthreads();

    // conv + relu + bn1
    for (int i = tid; i < 24 * T_; i += 256) {
        int oc = i / T_, t = i % T_;
        float acc = cb[oc];
        #pragma unroll
        for (int kk = 0; kk < 3; ++kk) {
            int tt = t + kk - 1;
            if (tt >= 0 && tt < T_) {
                #pragma unroll
                for (int ic = 0; ic < 9; ++ic)
                    acc += xs[tt * 17 + ic] * cw[(oc * 9 + ic) * 3 + kk];
            }
        }
        acc = fmaxf(acc, 0.f);
        acc = (acc - brm[oc]) * rsqrtf(brv[oc] + EPSF) * bg[oc] + bb[oc];
        ybuf[oc][t] = acc;
    }
    __syncthreads();

    // maxpool(2) -> feat[:, :24]
    for (int i = tid; i < TT * 24; i += 256) {
        int u = i / 24, oc = i % 24;
        feat[u][oc] = fmaxf(ybuf[oc][2 * u], ybuf[oc][2 * u + 1]);
    }
    // comp: relu(x[:, :30, 9:17] @ comp_w.T + b) -> feat[:, 24:44]
    for (int i = tid; i < TT * 20; i += 256) {
        int u = i / 20, oc = i % 20;
        float acc = compb[oc];
        #pragma unroll
        for (int j = 0; j < 8; ++j) acc += xs[u * 17 + 9 + j] * compw[oc * 8 + j];
        feat[u][24 + oc] = fmaxf(acc, 0.f);
    }
    __syncthreads();

    // proj: combined[b,u,hc] = feat[u,:] . pw[hc,:] + pb[hc]
    #pragma unroll
    for (int pass = 0; pass < 2; ++pass) {
        int hc = tid + pass * 256;
        float wreg[44];
        #pragma unroll
        for (int j = 0; j < 44; ++j) wreg[j] = pw[hc * 44 + j];
        float bias = pb[hc];
        for (int u = 0; u < TT; ++u) {
            const float4* fv = (const float4*)&feat[u][0];
            float a = bias;
            #pragma unroll
            for (int j4 = 0; j4 < 11; ++j4) {
                float4 f = fv[j4];
                a += f.x * wreg[4 * j4] + f.y * wreg[4 * j4 + 1] +
                     f.z * wreg[4 * j4 + 2] + f.w * wreg[4 * j4 + 3];
            }
            combined[((long)b * TT + u) * H_ + hc] = __float2bfloat16(a);
        }
    }
}

// ---------------------------------------------------------------------------
// bf16 MFMA GEMM: C[m,n] = sum_k A[m,k] * W[n,k] + bias[n]
// A split along K at `ksplit` between A0 (stride lda0) and A1 (stride lda1).
// W has row stride ldw (>= K) so K can be a prefix of the weight rows.
// 128x128 tile / block, BK=64, global_load_lds staging (m97 structure).
// ---------------------------------------------------------------------------
template <int WRITE_BF16>
__global__ __launch_bounds__(256)
void gemm_bias(const __hip_bfloat16* __restrict__ A0, int lda0,
               const __hip_bfloat16* __restrict__ A1, int lda1, int ksplit,
               const __hip_bfloat16* __restrict__ W, int ldw,
               const float* __restrict__ bias,
               void* __restrict__ Cout, int ldc, int K) {
    __shared__ __hip_bfloat16 As[128 * 64];
    __shared__ __hip_bfloat16 Bs[128 * 64];
    const int tid = threadIdx.x;
    const int wave = tid >> 6, lane = tid & 63;
    const long m0 = (long)blockIdx.y * 128;
    const long n0 = (long)blockIdx.x * 128;

    f32x4 acc[4][4] = {};

    for (int k0 = 0; k0 < K; k0 += 64) {
        __syncthreads();
        #pragma unroll
        for (int it = 0; it < 4; ++it) {
            int id = it * 256 + tid;          // 0..1023 -> 16 B each
            int row = id >> 3;                // 0..127
            int kc = (id & 7) << 3;           // 0..56
            int gk = k0 + kc;
            const __hip_bfloat16* srcA;
            if (gk < ksplit) srcA = A0 + (m0 + row) * (long)lda0 + gk;
            else             srcA = A1 + (m0 + row) * (long)lda1 + (gk - ksplit);
            async_load16(srcA, &As[id * 8]);
            const __hip_bfloat16* srcB = W + (n0 + row) * (long)ldw + gk;
            async_load16(srcB, &Bs[id * 8]);
        }
        __syncthreads();   // compiler emits vmcnt(0) drain before barrier
        #pragma unroll
        for (int ks = 0; ks < 2; ++ks) {
            const int kb = ks * 32 + (lane >> 4) * 8;
            const int ar = (wave >> 1) * 64 + (lane & 15);
            const int br = (wave & 1) * 64 + (lane & 15);
            bf16x8 afr[4], bfr[4];
            #pragma unroll
            for (int i = 0; i < 4; ++i) afr[i] = *(const bf16x8*)&As[(ar + i * 16) * 64 + kb];
            #pragma unroll
            for (int i = 0; i < 4; ++i) bfr[i] = *(const bf16x8*)&Bs[(br + i * 16) * 64 + kb];
            #pragma unroll
            for (int mi = 0; mi < 4; ++mi)
                #pragma unroll
                for (int ni = 0; ni < 4; ++ni)
                    acc[mi][ni] = __builtin_amdgcn_mfma_f32_16x16x32_bf16(afr[mi], bfr[ni], acc[mi][ni], 0, 0, 0);
        }
    }

    // epilogue: C/D layout col=lane&15, row=(lane>>4)*4+r
    const int cr = (lane >> 4) * 4;
    const int ccol = lane & 15;
    #pragma unroll
    for (int ni = 0; ni < 4; ++ni) {
        long col = n0 + (wave & 1) * 64 + ni * 16 + ccol;
        float bv = bias ? bias[col] : 0.f;
        #pragma unroll
        for (int mi = 0; mi < 4; ++mi) {
            long rowb = m0 + (wave >> 1) * 64 + mi * 16 + cr;
            #pragma unroll
            for (int r = 0; r < 4; ++r) {
                float v = acc[mi][ni][r] + bv;
                if (WRITE_BF16)
                    ((__hip_bfloat16*)Cout)[(rowb + r) * (long)ldc + col] = __float2bfloat16(v);
                else
                    ((float*)Cout)[(rowb + r) * (long)ldc + col] = v;
            }
        }
    }
}

// ---------------------------------------------------------------------------
// Gate elementwise + the two LayerNorms. One block (256 thr) per batch row.
// g: [B, 2560] f32 (f,i,o,cc,m blocks of 512). c: [B,512] f32 (updated).
// h written as bf16 with row stride hstride.
// ---------------------------------------------------------------------------
__device__ __forceinline__ void block_reduce2(float& a, float& b, float* red) {
    #pragma unroll
    for (int off = 32; off > 0; off >>= 1) {
        a += __shfl_down(a, off, 64);
        b += __shfl_down(b, off, 64);
    }
    int lane = threadIdx.x & 63, w = threadIdx.x >> 6;
    if (lane == 0) { red[w] = a; red[8 + w] = b; }
    __syncthreads();
    a = red[0] + red[1] + red[2] + red[3];
    b = red[8] + red[9] + red[10] + red[11];
    __syncthreads();
}

__global__ __launch_bounds__(256)
void gate_ew(const float* __restrict__ g, float* __restrict__ c,
             const float* __restrict__ ret,
             const float* __restrict__ elg, const float* __restrict__ elb,
             const float* __restrict__ lng, const float* __restrict__ lnb,
             __hip_bfloat16* __restrict__ hout, long hstride) {
    const int b = blockIdx.x, tid = threadIdx.x;
    const float* gr = g + (long)b * NGATE_;
    __shared__ float red[16];

    float o_[2], cn_[2];
    float s = 0.f, s2 = 0.f;
    #pragma unroll
    for (int u = 0; u < 2; ++u) {
        int j = tid + u * 256;
        float fg = gr[j], ig = gr[512 + j], og = gr[1024 + j];
        float cg = gr[1536 + j], mg = gr[2048 + j];
        float f = sigmoidf_(fg), i = sigmoidf_(ig), o = sigmoidf_(og);
        float cc = tanhf(cg), m = sigmoidf_(mg);
        float cold = c[(long)b * H_ + j];
        float r = ret[j];
        float cn = f * cold + i * cc;
        cn = cn * r + (1.f - r) * cold;
        cn = m * cn + (1.f - m) * cold;
        c[(long)b * H_ + j] = cn;
        o_[u] = o; cn_[u] = cn;
        s += o; s2 += o * o;
    }
    block_reduce2(s, s2, red);
    float mean = s * (1.f / H_);
    float var = s2 * (1.f / H_) - mean * mean;
    float rstd = rsqrtf(var + EPSF);

    float val[2];
    float s3 = 0.f, s4 = 0.f;
    #pragma unroll
    for (int u = 0; u < 2; ++u) {
        int j = tid + u * 256;
        float on = (o_[u] - mean) * rstd * elg[j] + elb[j];
        float oe = sigmoidf_(on);
        float v = oe * tanhf(cn_[u]);
        val[u] = v; s3 += v; s4 += v * v;
    }
    block_reduce2(s3, s4, red);
    float mean2 = s3 * (1.f / H_);
    float var2 = s4 * (1.f / H_) - mean2 * mean2;
    float rstd2 = rsqrtf(var2 + EPSF);
    #pragma unroll
    for (int u = 0; u < 2; ++u) {
        int j = tid + u * 256;
        float h = (val[u] - mean2) * rstd2 * lng[j] + lnb[j];
        hout[(long)b * hstride + j] = __float2bfloat16(h);
    }
}

// ---------------------------------------------------------------------------
// Attention for the last query only. One wave per (b, head), b chunk-local.
// kv: [KVCHUNK*30, 1024] bf16, cols 0..511 = k, 512..1023 = v.
// ---------------------------------------------------------------------------
__global__ __launch_bounds__(64)
void attn_kernel(const float* __restrict__ q, const __hip_bfloat16* __restrict__ kv,
                 __hip_bfloat16* __restrict__ outv) {
    const int bh = blockIdx.x;
    const int b = bh >> 2, h = bh & 3;
    const int l = threadIdx.x;
    const float scale = 0.0883883476483184f;  // 1/sqrt(128)
    float q0 = q[(long)b * H_ + h * DH_ + l];
    float q1 = q[(long)b * H_ + h * DH_ + 64 + l];
    __shared__ float p[32];
    for (int t = 0; t < TT; ++t) {
        const __hip_bfloat16* kp = kv + ((long)b * TT + t) * 1024 + h * DH_;
        float s = q0 * __bfloat162float(kp[l]) + q1 * __bfloat162float(kp[64 + l]);
        #pragma unroll
        for (int o = 32; o > 0; o >>= 1) s += __shfl_down(s, o, 64);
        if (l == 0) p[t] = s * scale;
    }
    __syncthreads();
    float mx = -1e30f;
    for (int t = 0; t < TT; ++t) mx = fmaxf(mx, p[t]);
    float den = 0.f;
    for (int t = 0; t < TT; ++t) den += __expf(p[t] - mx);
    float a0 = 0.f, a1 = 0.f;
    for (int t = 0; t < TT; ++t) {
        float wt = __expf(p[t] - mx);
        const __hip_bfloat16* vp = kv + ((long)b * TT + t) * 1024 + 512 + h * DH_;
        a0 += wt * __bfloat162float(vp[l]);
        a1 += wt * __bfloat162float(vp[64 + l]);
    }
    float inv = 1.f / den;
    outv[(long)b * H_ + h * DH_ + l] = __float2bfloat16(a0 * inv);
    outv[(long)b * H_ + h * DH_ + 64 + l] = __float2bfloat16(a1 * inv);
}

// ---------------------------------------------------------------------------
// Tail: bneck (512->128) + bn2 + out (128->14). One block per batch row.
// ---------------------------------------------------------------------------
__global__ __launch_bounds__(256)
void final_kernel(const float* __restrict__ fin,
                  const float* __restrict__ bw, const float* __restrict__ bb,
                  const float* __restrict__ g2, const float* __restrict__ b2,
                  const float* __restrict__ rm2, const float* __restrict__ rv2,
                  const float* __restrict__ ow, const float* __restrict__ ob,
                  float* __restrict__ out) {
    const int b = blockIdx.x, tid = threadIdx.x;
    __shared__ float fs[H_];
    __shared__ float lat[LAT_];
    fs[tid] = fin[(long)b * H_ + tid];
    fs[tid + 256] = fin[(long)b * H_ + 256 + tid];
    __syncthreads();
    if (tid < LAT_) {
        float a = bb[tid];
        const float4* w4 = (const float4*)(bw + tid * H_);
        const float4* f4 = (const float4*)fs;
        for (int j = 0; j < H_ / 4; ++j) {
            float4 w = w4[j], f = f4[j];
            a += f.x * w.x + f.y * w.y + f.z * w.z + f.w * w.w;
        }
        a = (a - rm2[tid]) * rsqrtf(rv2[tid] + EPSF) * g2[tid] + b2[tid];
        lat[tid] = a;
    }
    __syncthreads();
    if (tid < OUT_) {
        float a = ob[tid];
        #pragma unroll 4
        for (int j = 0; j < LAT_; ++j) a += lat[j] * ow[tid * LAT_ + j];
        out[(long)b * OUT_ + tid] = a;
    }
}

// ---------------------------------------------------------------------------
extern "C" void kernel_launch(void* const* d_in, const int* in_sizes, int n_in,
                              void* d_out, int out_size, void* d_ws, size_t ws_size,
                              hipStream_t stream) {
    const float* x        = (const float*)d_in[0];
    const float* conv1_w  = (const float*)d_in[1];
    const float* conv1_b  = (const float*)d_in[2];
    const float* bn1_g    = (const float*)d_in[3];
    const float* bn1_b    = (const float*)d_in[4];
    const float* bn1_rm   = (const float*)d_in[5];
    const float* bn1_rv   = (const float*)d_in[6];
    const float* comp_w   = (const float*)d_in[7];
    const float* comp_b   = (const float*)d_in[8];
    const float* proj_w   = (const float*)d_in[9];
    const float* proj_b   = (const float*)d_in[10];
    const float* gates_w  = (const float*)d_in[11];
    const float* gates_b  = (const float*)d_in[12];
    const float* retention= (const float*)d_in[13];
    const float* expln_g  = (const float*)d_in[14];
    const float* expln_b  = (const float*)d_in[15];
    const float* ln_g     = (const float*)d_in[16];
    const float* ln_b     = (const float*)d_in[17];
    const float* attn_in_w  = (const float*)d_in[18];
    const float* attn_in_b  = (const float*)d_in[19];
    const float* attn_out_w = (const float*)d_in[20];
    const float* attn_out_b = (const float*)d_in[21];
    const float* bneck_w  = (const float*)d_in[22];
    const float* bneck_b  = (const float*)d_in[23];
    const float* bn2_g    = (const float*)d_in[24];
    const float* bn2_b    = (const float*)d_in[25];
    const float* bn2_rm   = (const float*)d_in[26];
    const float* bn2_rv   = (const float*)d_in[27];
    const float* out_w    = (const float*)d_in[28];
    const float* out_b    = (const float*)d_in[29];
    float* out = (float*)d_out;

    // ---- compact workspace layout (~204 MiB total) ----
    char* base = (char*)d_ws;
    size_t off = 0;
    auto alloc = [&](size_t nbytes) -> char* {
        char* p = base + off;
        off += (nbytes + 255) & ~(size_t)255;
        return p;
    };
    // seq_bf doubles as combined: combined[:,t,:] is consumed (layer-0 GEMM)
    // before seq[:,t,:] is written (layer-1 gate_ew) within step t.
    __hip_bfloat16* seq_bf = (__hip_bfloat16*)alloc((size_t)B_ * TT * H_ * 2);   // 126 MB
    // union: f32 gate buffer (scan phase) / bf16 kv chunk (attention phase)
    size_t g_bytes  = (size_t)B_ * NGATE_ * 4;                                   // 42 MB
    size_t kv_bytes = (size_t)KVCHUNK * TT * 1024 * 2;                           // 31.4 MB
    char*  un = alloc(g_bytes > kv_bytes ? g_bytes : kv_bytes);
    float*          g_buf = (float*)un;
    __hip_bfloat16* kv_bf = (__hip_bfloat16*)un;
    float*          c0    = (float*)alloc((size_t)B_ * H_ * 4);   // c0,c1 contiguous
    float*          c1    = (float*)alloc((size_t)B_ * H_ * 4);
    __hip_bfloat16* h0_bf = (__hip_bfloat16*)alloc((size_t)B_ * H_ * 2);
    float*          q_f   = (float*)alloc((size_t)B_ * H_ * 4);   // reused as fin_f
    float*          fin_f = q_f;
    __hip_bfloat16* av_bf = (__hip_bfloat16*)alloc((size_t)B_ * H_ * 2);
    __hip_bfloat16* gw_bf = (__hip_bfloat16*)alloc((size_t)L_ * 5 * H_ * 2 * H_ * 2);
    __hip_bfloat16* ai_bf = (__hip_bfloat16*)alloc((size_t)3 * H_ * H_ * 2);
    __hip_bfloat16* ao_bf = (__hip_bfloat16*)alloc((size_t)H_ * H_ * 2);
    (void)ws_size; (void)in_sizes; (void)n_in; (void)out_size;

    // ---- weight conversion + state zeroing ----
    cvt_bf16<<<2048, 256, 0, stream>>>(gates_w, gw_bf, (long)L_ * 5 * H_ * 2 * H_);
    cvt_bf16<<<512, 256, 0, stream>>>(attn_in_w, ai_bf, (long)3 * H_ * H_);
    cvt_bf16<<<256, 256, 0, stream>>>(attn_out_w, ao_bf, (long)H_ * H_);
    zero_f32<<<2048, 256, 0, stream>>>(c0, (long)2 * B_ * H_);   // c0+c1 contiguous

    // ---- front-end ----
    frontend_kernel<<<B_, 256, 0, stream>>>(x, conv1_w, conv1_b, bn1_g, bn1_b, bn1_rm,
                                            bn1_rv, comp_w, comp_b, proj_w, proj_b,
                                            seq_bf);

    // ---- recurrent scan ----
    const int WL = 5 * H_ * 2 * H_;  // weight elems per layer
    const dim3 ggrid(NGATE_ / 128, B_ / 128);
    for (int t = 0; t < TT; ++t) {
        // layer 0: comb = [combined[:,t,:], h0] ; at t=0 h0==0 -> K=512 prefix
        if (t == 0) {
            gemm_bias<0><<<ggrid, 256, 0, stream>>>(
                seq_bf, TT * H_, (const __hip_bfloat16*)nullptr, 0, H_,
                gw_bf, 2 * H_, gates_b, (void*)g_buf, NGATE_, H_);
        } else {
            gemm_bias<0><<<ggrid, 256, 0, stream>>>(
                seq_bf + (size_t)t * H_, TT * H_, h0_bf, H_, H_,
                gw_bf, 2 * H_, gates_b, (void*)g_buf, NGATE_, 2 * H_);
        }
        gate_ew<<<B_, 256, 0, stream>>>(g_buf, c0, retention, expln_g, expln_b,
                                        ln_g, ln_b, h0_bf, H_);
        // layer 1: comb = [h0_new, h1_prev] ; at t=0 h1==0 -> K=512 prefix
        if (t == 0) {
            gemm_bias<0><<<ggrid, 256, 0, stream>>>(
                h0_bf, H_, (const __hip_bfloat16*)nullptr, 0, H_,
                gw_bf + WL, 2 * H_, gates_b + 5 * H_, (void*)g_buf, NGATE_, H_);
        } else {
            gemm_bias<0><<<ggrid, 256, 0, stream>>>(
                h0_bf, H_, seq_bf + (size_t)(t - 1) * H_, TT * H_, H_,
                gw_bf + WL, 2 * H_, gates_b + 5 * H_, (void*)g_buf, NGATE_, 2 * H_);
        }
        gate_ew<<<B_, 256, 0, stream>>>(g_buf, c1, retention + H_, expln_g + H_,
                                        expln_b + H_, ln_g + H_, ln_b + H_,
                                        seq_bf + (size_t)t * H_, TT * H_);
    }

    // ---- q projection (last timestep only) ----
    gemm_bias<0><<<dim3(H_ / 128, B_ / 128), 256, 0, stream>>>(
        seq_bf + (size_t)29 * H_, TT * H_, (const __hip_bfloat16*)nullptr, 0, H_,
        ai_bf, H_, attn_in_b, (void*)q_f, H_, H_);

    // ---- kv projection + attention, in 8 batch chunks of KVCHUNK rows ----
    for (int bc = 0; bc < B_ / KVCHUNK; ++bc) {
        const __hip_bfloat16* seq_c = seq_bf + (size_t)bc * KVCHUNK * TT * H_;
        gemm_bias<1><<<dim3(1024 / 128, (KVCHUNK * TT) / 128), 256, 0, stream>>>(
            seq_c, H_, (const __hip_bfloat16*)nullptr, 0, H_,
            ai_bf + (size_t)H_ * H_, H_, attn_in_b + H_, (void*)kv_bf, 2 * H_, H_);
        attn_kernel<<<KVCHUNK * NH_, 64, 0, stream>>>(
            q_f + (size_t)bc * KVCHUNK * H_, kv_bf, av_bf + (size_t)bc * KVCHUNK * H_);
    }

    // ---- attn_out projection (q_f no longer needed; fin_f aliases it) ----
    gemm_bias<0><<<dim3(H_ / 128, B_ / 128), 256, 0, stream>>>(
        av_bf, H_, (const __hip_bfloat16*)nullptr, 0, H_,
        ao_bf, H_, attn_out_b, (void*)fin_f, H_, H_);

    // ---- bneck + bn2 + head ----
    final_kernel<<<B_, 256, 0, stream>>>(fin_f, bneck_w, bneck_b, bn2_g, bn2_b,
                                         bn2_rm, bn2_rv, out_w, out_b, out);
}

// Round 3
// 4326.003 us; speedup vs baseline: 1.0384x; 1.0384x over previous
//
#include <hip/hip_runtime.h>
#include <hip/hip_bf16.h>

// Problem constants
#define B_   4096
#define T_   60
#define TT   30          // pooled sequence length
#define H_   512
#define L_   2
#define NH_  4
#define DH_  128
#define LAT_ 128
#define OUT_ 14
#define NGATE_ (5*H_)    // 2560
#define EPSF 1e-5f
#define KVCHUNK 512      // batch rows per kv chunk (8 chunks)
#define FEATK 64         // feat padded to 64 (GEMM K granularity)

typedef __attribute__((ext_vector_type(8))) short bf16x8;
typedef __attribute__((ext_vector_type(4))) float f32x4;

__device__ __forceinline__ float sigmoidf_(float x) { return 1.0f / (1.0f + __expf(-x)); }

__device__ __forceinline__ void async_load16(const void* g, void* l) {
    __builtin_amdgcn_global_load_lds((const __attribute__((address_space(1))) void*)g,
                                     (__attribute__((address_space(3))) void*)l, 16, 0, 0);
}

// ---------------------------------------------------------------------------
// Utility kernels
// ---------------------------------------------------------------------------
__global__ __launch_bounds__(256) void cvt_bf16(const float* __restrict__ in,
                                                __hip_bfloat16* __restrict__ out, long n) {
    long i = (long)blockIdx.x * blockDim.x + threadIdx.x;
    long stride = (long)gridDim.x * blockDim.x;
    for (; i < n; i += stride) out[i] = __float2bfloat16(in[i]);
}

__global__ __launch_bounds__(256) void zero_f32(float* __restrict__ p, long n) {
    long i = (long)blockIdx.x * blockDim.x + threadIdx.x;
    long stride = (long)gridDim.x * blockDim.x;
    for (; i < n; i += stride) p[i] = 0.0f;
}

// proj_w [512,44] f32 -> padded [512,64] bf16 (cols 44..63 zero)
__global__ __launch_bounds__(256) void pad_projw(const float* __restrict__ pw,
                                                 __hip_bfloat16* __restrict__ out) {
    int i = blockIdx.x * 256 + threadIdx.x;      // 512*64 = 32768
    if (i >= H_ * FEATK) return;
    int r = i >> 6, c = i & 63;
    out[i] = __float2bfloat16(c < 44 ? pw[r * 44 + c] : 0.f);
}

// ---------------------------------------------------------------------------
// Front-end: conv1d(9->24,k3,p1)+relu+bn -> maxpool2 -> concat comp(8->20 relu)
// Writes feat [B*TT, 64] bf16 (cols 44..63 zero). Proj happens via MFMA GEMM.
// ---------------------------------------------------------------------------
__global__ __launch_bounds__(256)
void frontend_kernel(const float* __restrict__ x,
                     const float* __restrict__ cw, const float* __restrict__ cb,
                     const float* __restrict__ bg, const float* __restrict__ bb,
                     const float* __restrict__ brm, const float* __restrict__ brv,
                     const float* __restrict__ compw, const float* __restrict__ compb,
                     __hip_bfloat16* __restrict__ feat_out) {
    const int b = blockIdx.x, tid = threadIdx.x;
    __shared__ float xs[T_ * 17];        // 4080 B
    __shared__ float ybuf[24][T_];       // 5760 B
    __shared__ float feat[TT][44];       // 5280 B

    for (int i = tid; i < T_ * 17; i += 256) xs[i] = x[(long)b * T_ * 17 + i];
    __syncthreads();

    // conv + relu + bn1
    for (int i = tid; i < 24 * T_; i += 256) {
        int oc = i / T_, t = i % T_;
        float acc = cb[oc];
        #pragma unroll
        for (int kk = 0; kk < 3; ++kk) {
            int tt = t + kk - 1;
            if (tt >= 0 && tt < T_) {
                #pragma unroll
                for (int ic = 0; ic < 9; ++ic)
                    acc += xs[tt * 17 + ic] * cw[(oc * 9 + ic) * 3 + kk];
            }
        }
        acc = fmaxf(acc, 0.f);
        acc = (acc - brm[oc]) * rsqrtf(brv[oc] + EPSF) * bg[oc] + bb[oc];
        ybuf[oc][t] = acc;
    }
    __syncthreads();

    // maxpool(2) -> feat[:, :24]
    for (int i = tid; i < TT * 24; i += 256) {
        int u = i / 24, oc = i % 24;
        feat[u][oc] = fmaxf(ybuf[oc][2 * u], ybuf[oc][2 * u + 1]);
    }
    // comp: relu(x[:, :30, 9:17] @ comp_w.T + b) -> feat[:, 24:44]
    for (int i = tid; i < TT * 20; i += 256) {
        int u = i / 20, oc = i % 20;
        float acc = compb[oc];
        #pragma unroll
        for (int j = 0; j < 8; ++j) acc += xs[u * 17 + 9 + j] * compw[oc * 8 + j];
        feat[u][24 + oc] = fmaxf(acc, 0.f);
    }
    __syncthreads();

    // write padded bf16 feat rows
    for (int i = tid; i < TT * FEATK; i += 256) {
        int u = i >> 6, c = i & 63;
        float v = (c < 44) ? feat[u][c] : 0.f;
        feat_out[((long)b * TT + u) * FEATK + c] = __float2bfloat16(v);
    }
}

// ---------------------------------------------------------------------------
// bf16 MFMA GEMM: C[m,n] = sum_k A[m,k] * W[n,k] + bias[n]
// A split along K at `ksplit` between A0 (stride lda0) and A1 (stride lda1).
// W has row stride ldw (>= K) so K can be a prefix of the weight rows.
// 128x128 tile / block, BK=64, global_load_lds staging (m97 structure).
// ---------------------------------------------------------------------------
template <int WRITE_BF16>
__global__ __launch_bounds__(256)
void gemm_bias(const __hip_bfloat16* __restrict__ A0, int lda0,
               const __hip_bfloat16* __restrict__ A1, int lda1, int ksplit,
               const __hip_bfloat16* __restrict__ W, int ldw,
               const float* __restrict__ bias,
               void* __restrict__ Cout, int ldc, int K) {
    __shared__ __hip_bfloat16 As[128 * 64];
    __shared__ __hip_bfloat16 Bs[128 * 64];
    const int tid = threadIdx.x;
    const int wave = tid >> 6, lane = tid & 63;
    const long m0 = (long)blockIdx.y * 128;
    const long n0 = (long)blockIdx.x * 128;

    f32x4 acc[4][4] = {};

    for (int k0 = 0; k0 < K; k0 += 64) {
        __syncthreads();
        #pragma unroll
        for (int it = 0; it < 4; ++it) {
            int id = it * 256 + tid;          // 0..1023 -> 16 B each
            int row = id >> 3;                // 0..127
            int kc = (id & 7) << 3;           // 0..56
            int gk = k0 + kc;
            const __hip_bfloat16* srcA;
            if (gk < ksplit) srcA = A0 + (m0 + row) * (long)lda0 + gk;
            else             srcA = A1 + (m0 + row) * (long)lda1 + (gk - ksplit);
            async_load16(srcA, &As[id * 8]);
            const __hip_bfloat16* srcB = W + (n0 + row) * (long)ldw + gk;
            async_load16(srcB, &Bs[id * 8]);
        }
        __syncthreads();
        #pragma unroll
        for (int ks = 0; ks < 2; ++ks) {
            const int kb = ks * 32 + (lane >> 4) * 8;
            const int ar = (wave >> 1) * 64 + (lane & 15);
            const int br = (wave & 1) * 64 + (lane & 15);
            bf16x8 afr[4], bfr[4];
            #pragma unroll
            for (int i = 0; i < 4; ++i) afr[i] = *(const bf16x8*)&As[(ar + i * 16) * 64 + kb];
            #pragma unroll
            for (int i = 0; i < 4; ++i) bfr[i] = *(const bf16x8*)&Bs[(br + i * 16) * 64 + kb];
            #pragma unroll
            for (int mi = 0; mi < 4; ++mi)
                #pragma unroll
                for (int ni = 0; ni < 4; ++ni)
                    acc[mi][ni] = __builtin_amdgcn_mfma_f32_16x16x32_bf16(afr[mi], bfr[ni], acc[mi][ni], 0, 0, 0);
        }
    }

    // epilogue: C/D layout col=lane&15, row=(lane>>4)*4+r
    const int cr = (lane >> 4) * 4;
    const int ccol = lane & 15;
    #pragma unroll
    for (int ni = 0; ni < 4; ++ni) {
        long col = n0 + (wave & 1) * 64 + ni * 16 + ccol;
        float bv = bias ? bias[col] : 0.f;
        #pragma unroll
        for (int mi = 0; mi < 4; ++mi) {
            long rowb = m0 + (wave >> 1) * 64 + mi * 16 + cr;
            #pragma unroll
            for (int r = 0; r < 4; ++r) {
                float v = acc[mi][ni][r] + bv;
                if (WRITE_BF16)
                    ((__hip_bfloat16*)Cout)[(rowb + r) * (long)ldc + col] = __float2bfloat16(v);
                else
                    ((float*)Cout)[(rowb + r) * (long)ldc + col] = v;
            }
        }
    }
}

// ---------------------------------------------------------------------------
// Gate elementwise + the two LayerNorms. One block (256 thr) per batch row.
// g: [B, 2560] bf16 (f,i,o,cc,m blocks of 512). c: [B,512] f32 (updated).
// h written as bf16 with row stride hstride.
// ---------------------------------------------------------------------------
__device__ __forceinline__ void block_reduce2(float& a, float& b, float* red) {
    #pragma unroll
    for (int off = 32; off > 0; off >>= 1) {
        a += __shfl_down(a, off, 64);
        b += __shfl_down(b, off, 64);
    }
    int lane = threadIdx.x & 63, w = threadIdx.x >> 6;
    if (lane == 0) { red[w] = a; red[8 + w] = b; }
    __syncthreads();
    a = red[0] + red[1] + red[2] + red[3];
    b = red[8] + red[9] + red[10] + red[11];
    __syncthreads();
}

__global__ __launch_bounds__(256)
void gate_ew(const __hip_bfloat16* __restrict__ g, float* __restrict__ c,
             const float* __restrict__ ret,
             const float* __restrict__ elg, const float* __restrict__ elb,
             const float* __restrict__ lng, const float* __restrict__ lnb,
             __hip_bfloat16* __restrict__ hout, long hstride) {
    const int b = blockIdx.x, tid = threadIdx.x;
    const __hip_bfloat16* gr = g + (long)b * NGATE_;
    __shared__ float red[16];

    float o_[2], cn_[2];
    float s = 0.f, s2 = 0.f;
    #pragma unroll
    for (int u = 0; u < 2; ++u) {
        int j = tid + u * 256;
        float fg = __bfloat162float(gr[j]);
        float ig = __bfloat162float(gr[512 + j]);
        float og = __bfloat162float(gr[1024 + j]);
        float cg = __bfloat162float(gr[1536 + j]);
        float mg = __bfloat162float(gr[2048 + j]);
        float f = sigmoidf_(fg), i = sigmoidf_(ig), o = sigmoidf_(og);
        float cc = tanhf(cg), m = sigmoidf_(mg);
        float cold = c[(long)b * H_ + j];
        float r = ret[j];
        float cn = f * cold + i * cc;
        cn = cn * r + (1.f - r) * cold;
        cn = m * cn + (1.f - m) * cold;
        c[(long)b * H_ + j] = cn;
        o_[u] = o; cn_[u] = cn;
        s += o; s2 += o * o;
    }
    block_reduce2(s, s2, red);
    float mean = s * (1.f / H_);
    float var = s2 * (1.f / H_) - mean * mean;
    float rstd = rsqrtf(var + EPSF);

    float val[2];
    float s3 = 0.f, s4 = 0.f;
    #pragma unroll
    for (int u = 0; u < 2; ++u) {
        int j = tid + u * 256;
        float on = (o_[u] - mean) * rstd * elg[j] + elb[j];
        float oe = sigmoidf_(on);
        float v = oe * tanhf(cn_[u]);
        val[u] = v; s3 += v; s4 += v * v;
    }
    block_reduce2(s3, s4, red);
    float mean2 = s3 * (1.f / H_);
    float var2 = s4 * (1.f / H_) - mean2 * mean2;
    float rstd2 = rsqrtf(var2 + EPSF);
    #pragma unroll
    for (int u = 0; u < 2; ++u) {
        int j = tid + u * 256;
        float h = (val[u] - mean2) * rstd2 * lng[j] + lnb[j];
        hout[(long)b * hstride + j] = __float2bfloat16(h);
    }
}

// ---------------------------------------------------------------------------
// Attention for the last query only. One wave per (b, head), b chunk-local.
// kv: [KVCHUNK*30, 1024] bf16, cols 0..511 = k, 512..1023 = v.
// ---------------------------------------------------------------------------
__global__ __launch_bounds__(64)
void attn_kernel(const float* __restrict__ q, const __hip_bfloat16* __restrict__ kv,
                 __hip_bfloat16* __restrict__ outv) {
    const int bh = blockIdx.x;
    const int b = bh >> 2, h = bh & 3;
    const int l = threadIdx.x;
    const float scale = 0.0883883476483184f;  // 1/sqrt(128)
    float q0 = q[(long)b * H_ + h * DH_ + l];
    float q1 = q[(long)b * H_ + h * DH_ + 64 + l];
    __shared__ float p[32];
    for (int t = 0; t < TT; ++t) {
        const __hip_bfloat16* kp = kv + ((long)b * TT + t) * 1024 + h * DH_;
        float s = q0 * __bfloat162float(kp[l]) + q1 * __bfloat162float(kp[64 + l]);
        #pragma unroll
        for (int o = 32; o > 0; o >>= 1) s += __shfl_down(s, o, 64);
        if (l == 0) p[t] = s * scale;
    }
    __syncthreads();
    float mx = -1e30f;
    for (int t = 0; t < TT; ++t) mx = fmaxf(mx, p[t]);
    float den = 0.f;
    for (int t = 0; t < TT; ++t) den += __expf(p[t] - mx);
    float a0 = 0.f, a1 = 0.f;
    for (int t = 0; t < TT; ++t) {
        float wt = __expf(p[t] - mx);
        const __hip_bfloat16* vp = kv + ((long)b * TT + t) * 1024 + 512 + h * DH_;
        a0 += wt * __bfloat162float(vp[l]);
        a1 += wt * __bfloat162float(vp[64 + l]);
    }
    float inv = 1.f / den;
    outv[(long)b * H_ + h * DH_ + l] = __float2bfloat16(a0 * inv);
    outv[(long)b * H_ + h * DH_ + 64 + l] = __float2bfloat16(a1 * inv);
}

// ---------------------------------------------------------------------------
// Tail: bneck (512->128) + bn2 + out (128->14). One block per batch row.
// ---------------------------------------------------------------------------
__global__ __launch_bounds__(256)
void final_kernel(const float* __restrict__ fin,
                  const float* __restrict__ bw, const float* __restrict__ bb,
                  const float* __restrict__ g2, const float* __restrict__ b2,
                  const float* __restrict__ rm2, const float* __restrict__ rv2,
                  const float* __restrict__ ow, const float* __restrict__ ob,
                  float* __restrict__ out) {
    const int b = blockIdx.x, tid = threadIdx.x;
    __shared__ float fs[H_];
    __shared__ float lat[LAT_];
    fs[tid] = fin[(long)b * H_ + tid];
    fs[tid + 256] = fin[(long)b * H_ + 256 + tid];
    __syncthreads();
    if (tid < LAT_) {
        float a = bb[tid];
        const float4* w4 = (const float4*)(bw + tid * H_);
        const float4* f4 = (const float4*)fs;
        for (int j = 0; j < H_ / 4; ++j) {
            float4 w = w4[j], f = f4[j];
            a += f.x * w.x + f.y * w.y + f.z * w.z + f.w * w.w;
        }
        a = (a - rm2[tid]) * rsqrtf(rv2[tid] + EPSF) * g2[tid] + b2[tid];
        lat[tid] = a;
    }
    __syncthreads();
    if (tid < OUT_) {
        float a = ob[tid];
        #pragma unroll 4
        for (int j = 0; j < LAT_; ++j) a += lat[j] * ow[tid * LAT_ + j];
        out[(long)b * OUT_ + tid] = a;
    }
}

// ---------------------------------------------------------------------------
extern "C" void kernel_launch(void* const* d_in, const int* in_sizes, int n_in,
                              void* d_out, int out_size, void* d_ws, size_t ws_size,
                              hipStream_t stream) {
    const float* x        = (const float*)d_in[0];
    const float* conv1_w  = (const float*)d_in[1];
    const float* conv1_b  = (const float*)d_in[2];
    const float* bn1_g    = (const float*)d_in[3];
    const float* bn1_b    = (const float*)d_in[4];
    const float* bn1_rm   = (const float*)d_in[5];
    const float* bn1_rv   = (const float*)d_in[6];
    const float* comp_w   = (const float*)d_in[7];
    const float* comp_b   = (const float*)d_in[8];
    const float* proj_w   = (const float*)d_in[9];
    const float* proj_b   = (const float*)d_in[10];
    const float* gates_w  = (const float*)d_in[11];
    const float* gates_b  = (const float*)d_in[12];
    const float* retention= (const float*)d_in[13];
    const float* expln_g  = (const float*)d_in[14];
    const float* expln_b  = (const float*)d_in[15];
    const float* ln_g     = (const float*)d_in[16];
    const float* ln_b     = (const float*)d_in[17];
    const float* attn_in_w  = (const float*)d_in[18];
    const float* attn_in_b  = (const float*)d_in[19];
    const float* attn_out_w = (const float*)d_in[20];
    const float* attn_out_b = (const float*)d_in[21];
    const float* bneck_w  = (const float*)d_in[22];
    const float* bneck_b  = (const float*)d_in[23];
    const float* bn2_g    = (const float*)d_in[24];
    const float* bn2_b    = (const float*)d_in[25];
    const float* bn2_rm   = (const float*)d_in[26];
    const float* bn2_rv   = (const float*)d_in[27];
    const float* out_w    = (const float*)d_in[28];
    const float* out_b    = (const float*)d_in[29];
    float* out = (float*)d_out;

    // ---- compact workspace layout (~214 MiB total) ----
    char* base = (char*)d_ws;
    size_t off = 0;
    auto alloc = [&](size_t nbytes) -> char* {
        char* p = base + off;
        off += (nbytes + 255) & ~(size_t)255;
        return p;
    };
    // seq_bf doubles as combined: combined[:,t,:] is consumed (layer-0 GEMM)
    // before seq[:,t,:] is written (layer-1 gate_ew) within step t.
    __hip_bfloat16* seq_bf = (__hip_bfloat16*)alloc((size_t)B_ * TT * H_ * 2);   // 126 MB
    // union: feat (front-end) / bf16 gate buffer (scan) / kv chunk (attention)
    size_t feat_bytes = (size_t)B_ * TT * FEATK * 2;                             // 15.7 MB
    size_t g_bytes    = (size_t)B_ * NGATE_ * 2;                                 // 21 MB
    size_t kv_bytes   = (size_t)KVCHUNK * TT * 1024 * 2;                         // 31.4 MB
    size_t un_bytes = feat_bytes > g_bytes ? feat_bytes : g_bytes;
    if (kv_bytes > un_bytes) un_bytes = kv_bytes;
    char* un = alloc(un_bytes);
    __hip_bfloat16* feat_bf = (__hip_bfloat16*)un;
    __hip_bfloat16* g_bf    = (__hip_bfloat16*)un;
    __hip_bfloat16* kv_bf   = (__hip_bfloat16*)un;
    float*          c0    = (float*)alloc((size_t)B_ * H_ * 4);   // c0,c1 contiguous
    float*          c1    = (float*)alloc((size_t)B_ * H_ * 4);
    __hip_bfloat16* h0_bf = (__hip_bfloat16*)alloc((size_t)B_ * H_ * 2);
    float*          q_f   = (float*)alloc((size_t)B_ * H_ * 4);   // reused as fin_f
    float*          fin_f = q_f;
    __hip_bfloat16* av_bf = (__hip_bfloat16*)alloc((size_t)B_ * H_ * 2);
    __hip_bfloat16* gw_bf = (__hip_bfloat16*)alloc((size_t)L_ * 5 * H_ * 2 * H_ * 2);
    __hip_bfloat16* ai_bf = (__hip_bfloat16*)alloc((size_t)3 * H_ * H_ * 2);
    __hip_bfloat16* ao_bf = (__hip_bfloat16*)alloc((size_t)H_ * H_ * 2);
    __hip_bfloat16* pw_bf = (__hip_bfloat16*)alloc((size_t)H_ * FEATK * 2);
    (void)ws_size; (void)in_sizes; (void)n_in; (void)out_size;

    // ---- weight conversion + state zeroing ----
    cvt_bf16<<<2048, 256, 0, stream>>>(gates_w, gw_bf, (long)L_ * 5 * H_ * 2 * H_);
    cvt_bf16<<<512, 256, 0, stream>>>(attn_in_w, ai_bf, (long)3 * H_ * H_);
    cvt_bf16<<<256, 256, 0, stream>>>(attn_out_w, ao_bf, (long)H_ * H_);
    pad_projw<<<(H_ * FEATK + 255) / 256, 256, 0, stream>>>(proj_w, pw_bf);
    zero_f32<<<2048, 256, 0, stream>>>(c0, (long)2 * B_ * H_);   // c0+c1 contiguous

    // ---- front-end: feat, then proj via MFMA GEMM ----
    frontend_kernel<<<B_, 256, 0, stream>>>(x, conv1_w, conv1_b, bn1_g, bn1_b, bn1_rm,
                                            bn1_rv, comp_w, comp_b, feat_bf);
    gemm_bias<1><<<dim3(H_ / 128, (B_ * TT) / 128), 256, 0, stream>>>(
        feat_bf, FEATK, (const __hip_bfloat16*)nullptr, 0, FEATK,
        pw_bf, FEATK, proj_b, (void*)seq_bf, H_, FEATK);

    // ---- recurrent scan ----
    const int WL = 5 * H_ * 2 * H_;  // weight elems per layer
    const dim3 ggrid(NGATE_ / 128, B_ / 128);
    for (int t = 0; t < TT; ++t) {
        // layer 0: comb = [combined[:,t,:], h0] ; at t=0 h0==0 -> K=512 prefix
        if (t == 0) {
            gemm_bias<1><<<ggrid, 256, 0, stream>>>(
                seq_bf, TT * H_, (const __hip_bfloat16*)nullptr, 0, H_,
                gw_bf, 2 * H_, gates_b, (void*)g_bf, NGATE_, H_);
        } else {
            gemm_bias<1><<<ggrid, 256, 0, stream>>>(
                seq_bf + (size_t)t * H_, TT * H_, h0_bf, H_, H_,
                gw_bf, 2 * H_, gates_b, (void*)g_bf, NGATE_, 2 * H_);
        }
        gate_ew<<<B_, 256, 0, stream>>>(g_bf, c0, retention, expln_g, expln_b,
                                        ln_g, ln_b, h0_bf, H_);
        // layer 1: comb = [h0_new, h1_prev] ; at t=0 h1==0 -> K=512 prefix
        if (t == 0) {
            gemm_bias<1><<<ggrid, 256, 0, stream>>>(
                h0_bf, H_, (const __hip_bfloat16*)nullptr, 0, H_,
                gw_bf + WL, 2 * H_, gates_b + 5 * H_, (void*)g_bf, NGATE_, H_);
        } else {
            gemm_bias<1><<<ggrid, 256, 0, stream>>>(
                h0_bf, H_, seq_bf + (size_t)(t - 1) * H_, TT * H_, H_,
                gw_bf + WL, 2 * H_, gates_b + 5 * H_, (void*)g_bf, NGATE_, 2 * H_);
        }
        gate_ew<<<B_, 256, 0, stream>>>(g_bf, c1, retention + H_, expln_g + H_,
                                        expln_b + H_, ln_g + H_, ln_b + H_,
                                        seq_bf + (size_t)t * H_, TT * H_);
    }

    // ---- q projection (last timestep only) ----
    gemm_bias<0><<<dim3(H_ / 128, B_ / 128), 256, 0, stream>>>(
        seq_bf + (size_t)29 * H_, TT * H_, (const __hip_bfloat16*)nullptr, 0, H_,
        ai_bf, H_, attn_in_b, (void*)q_f, H_, H_);

    // ---- kv projection + attention, in 8 batch chunks of KVCHUNK rows ----
    for (int bc = 0; bc < B_ / KVCHUNK; ++bc) {
        const __hip_bfloat16* seq_c = seq_bf + (size_t)bc * KVCHUNK * TT * H_;
        gemm_bias<1><<<dim3(1024 / 128, (KVCHUNK * TT) / 128), 256, 0, stream>>>(
            seq_c, H_, (const __hip_bfloat16*)nullptr, 0, H_,
            ai_bf + (size_t)H_ * H_, H_, attn_in_b + H_, (void*)kv_bf, 2 * H_, H_);
        attn_kernel<<<KVCHUNK * NH_, 64, 0, stream>>>(
            q_f + (size_t)bc * KVCHUNK * H_, kv_bf, av_bf + (size_t)bc * KVCHUNK * H_);
    }

    // ---- attn_out projection (q_f no longer needed; fin_f aliases it) ----
    gemm_bias<0><<<dim3(H_ / 128, B_ / 128), 256, 0, stream>>>(
        av_bf, H_, (const __hip_bfloat16*)nullptr, 0, H_,
        ao_bf, H_, attn_out_b, (void*)fin_f, H_, H_);

    // ---- bneck + bn2 + head ----
    final_kernel<<<B_, 256, 0, stream>>>(fin_f, bneck_w, bneck_b, bn2_g, bn2_b,
                                         bn2_rm, bn2_rv, out_w, out_b, out);
}

// Round 4
// 3580.576 us; speedup vs baseline: 1.2545x; 1.2082x over previous
//
#include <hip/hip_runtime.h>
#include <hip/hip_bf16.h>

// Problem constants
#define B_   4096
#define T_   60
#define TT   30          // pooled sequence length
#define H_   512
#define L_   2
#define NH_  4
#define DH_  128
#define LAT_ 128
#define OUT_ 14
#define NGATE_ (5*H_)    // 2560
#define EPSF 1e-5f
#define KVCHUNK 512      // batch rows per kv chunk (8 chunks)
#define FEATK 64         // feat padded to 64 (GEMM K granularity)

typedef __attribute__((ext_vector_type(8))) short bf16x8;
typedef __attribute__((ext_vector_type(4))) float f32x4;

__device__ __forceinline__ float sigmoidf_(float x) { return 1.0f / (1.0f + __expf(-x)); }

__device__ __forceinline__ void async_load16(const void* g, void* l) {
    __builtin_amdgcn_global_load_lds((const __attribute__((address_space(1))) void*)g,
                                     (__attribute__((address_space(3))) void*)l, 16, 0, 0);
}

// ---------------------------------------------------------------------------
// Utility kernels
// ---------------------------------------------------------------------------
__global__ __launch_bounds__(256) void cvt_bf16(const float* __restrict__ in,
                                                __hip_bfloat16* __restrict__ out, long n) {
    long i = (long)blockIdx.x * blockDim.x + threadIdx.x;
    long stride = (long)gridDim.x * blockDim.x;
    for (; i < n; i += stride) out[i] = __float2bfloat16(in[i]);
}

__global__ __launch_bounds__(256) void zero_f32(float* __restrict__ p, long n) {
    long i = (long)blockIdx.x * blockDim.x + threadIdx.x;
    long stride = (long)gridDim.x * blockDim.x;
    for (; i < n; i += stride) p[i] = 0.0f;
}

// proj_w [512,44] f32 -> padded [512,64] bf16 (cols 44..63 zero)
__global__ __launch_bounds__(256) void pad_projw(const float* __restrict__ pw,
                                                 __hip_bfloat16* __restrict__ out) {
    int i = blockIdx.x * 256 + threadIdx.x;      // 512*64 = 32768
    if (i >= H_ * FEATK) return;
    int r = i >> 6, c = i & 63;
    out[i] = __float2bfloat16(c < 44 ? pw[r * 44 + c] : 0.f);
}

// ---------------------------------------------------------------------------
// Front-end: conv1d(9->24,k3,p1)+relu+bn -> maxpool2 -> concat comp(8->20 relu)
// Writes feat [B*TT, 64] bf16 (cols 44..63 zero). Proj happens via MFMA GEMM.
// ---------------------------------------------------------------------------
__global__ __launch_bounds__(256)
void frontend_kernel(const float* __restrict__ x,
                     const float* __restrict__ cw, const float* __restrict__ cb,
                     const float* __restrict__ bg, const float* __restrict__ bb,
                     const float* __restrict__ brm, const float* __restrict__ brv,
                     const float* __restrict__ compw, const float* __restrict__ compb,
                     __hip_bfloat16* __restrict__ feat_out) {
    const int b = blockIdx.x, tid = threadIdx.x;
    __shared__ float xs[T_ * 17];        // 4080 B
    __shared__ float ybuf[24][T_];       // 5760 B
    __shared__ float feat[TT][44];       // 5280 B

    for (int i = tid; i < T_ * 17; i += 256) xs[i] = x[(long)b * T_ * 17 + i];
    __syncthreads();

    // conv + relu + bn1
    for (int i = tid; i < 24 * T_; i += 256) {
        int oc = i / T_, t = i % T_;
        float acc = cb[oc];
        #pragma unroll
        for (int kk = 0; kk < 3; ++kk) {
            int tt = t + kk - 1;
            if (tt >= 0 && tt < T_) {
                #pragma unroll
                for (int ic = 0; ic < 9; ++ic)
                    acc += xs[tt * 17 + ic] * cw[(oc * 9 + ic) * 3 + kk];
            }
        }
        acc = fmaxf(acc, 0.f);
        acc = (acc - brm[oc]) * rsqrtf(brv[oc] + EPSF) * bg[oc] + bb[oc];
        ybuf[oc][t] = acc;
    }
    __syncthreads();

    // maxpool(2) -> feat[:, :24]
    for (int i = tid; i < TT * 24; i += 256) {
        int u = i / 24, oc = i % 24;
        feat[u][oc] = fmaxf(ybuf[oc][2 * u], ybuf[oc][2 * u + 1]);
    }
    // comp: relu(x[:, :30, 9:17] @ comp_w.T + b) -> feat[:, 24:44]
    for (int i = tid; i < TT * 20; i += 256) {
        int u = i / 20, oc = i % 20;
        float acc = compb[oc];
        #pragma unroll
        for (int j = 0; j < 8; ++j) acc += xs[u * 17 + 9 + j] * compw[oc * 8 + j];
        feat[u][24 + oc] = fmaxf(acc, 0.f);
    }
    __syncthreads();

    // write padded bf16 feat rows
    for (int i = tid; i < TT * FEATK; i += 256) {
        int u = i >> 6, c = i & 63;
        float v = (c < 44) ? feat[u][c] : 0.f;
        feat_out[((long)b * TT + u) * FEATK + c] = __float2bfloat16(v);
    }
}

// ---------------------------------------------------------------------------
// bf16 MFMA GEMM core: C[m,n] = sum_k A[m,k] * W[n,k] + bias[n]
// A split along K at `ksplit` between A0 (stride lda0) and A1 (stride lda1).
// W has row stride ldw (>= K). 128x128 tile, BK=64, global_load_lds staging.
// ---------------------------------------------------------------------------
template <int WRITE_BF16>
__device__ __forceinline__
void gemm_core(const __hip_bfloat16* __restrict__ A0, int lda0,
               const __hip_bfloat16* __restrict__ A1, int lda1, int ksplit,
               const __hip_bfloat16* __restrict__ W, int ldw,
               const float* __restrict__ bias,
               void* __restrict__ Cout, int ldc, int K, int bx, int by) {
    __shared__ __hip_bfloat16 As[128 * 64];
    __shared__ __hip_bfloat16 Bs[128 * 64];
    const int tid = threadIdx.x;
    const int wave = tid >> 6, lane = tid & 63;
    const long m0 = (long)by * 128;
    const long n0 = (long)bx * 128;

    f32x4 acc[4][4] = {};

    for (int k0 = 0; k0 < K; k0 += 64) {
        __syncthreads();
        #pragma unroll
        for (int it = 0; it < 4; ++it) {
            int id = it * 256 + tid;          // 0..1023 -> 16 B each
            int row = id >> 3;                // 0..127
            int kc = (id & 7) << 3;           // 0..56
            int gk = k0 + kc;
            const __hip_bfloat16* srcA;
            if (gk < ksplit) srcA = A0 + (m0 + row) * (long)lda0 + gk;
            else             srcA = A1 + (m0 + row) * (long)lda1 + (gk - ksplit);
            async_load16(srcA, &As[id * 8]);
            const __hip_bfloat16* srcB = W + (n0 + row) * (long)ldw + gk;
            async_load16(srcB, &Bs[id * 8]);
        }
        __syncthreads();
        #pragma unroll
        for (int ks = 0; ks < 2; ++ks) {
            const int kb = ks * 32 + (lane >> 4) * 8;
            const int ar = (wave >> 1) * 64 + (lane & 15);
            const int br = (wave & 1) * 64 + (lane & 15);
            bf16x8 afr[4], bfr[4];
            #pragma unroll
            for (int i = 0; i < 4; ++i) afr[i] = *(const bf16x8*)&As[(ar + i * 16) * 64 + kb];
            #pragma unroll
            for (int i = 0; i < 4; ++i) bfr[i] = *(const bf16x8*)&Bs[(br + i * 16) * 64 + kb];
            #pragma unroll
            for (int mi = 0; mi < 4; ++mi)
                #pragma unroll
                for (int ni = 0; ni < 4; ++ni)
                    acc[mi][ni] = __builtin_amdgcn_mfma_f32_16x16x32_bf16(afr[mi], bfr[ni], acc[mi][ni], 0, 0, 0);
        }
    }

    // epilogue: C/D layout col=lane&15, row=(lane>>4)*4+r
    const int cr = (lane >> 4) * 4;
    const int ccol = lane & 15;
    #pragma unroll
    for (int ni = 0; ni < 4; ++ni) {
        long col = n0 + (wave & 1) * 64 + ni * 16 + ccol;
        float bv = bias ? bias[col] : 0.f;
        #pragma unroll
        for (int mi = 0; mi < 4; ++mi) {
            long rowb = m0 + (wave >> 1) * 64 + mi * 16 + cr;
            #pragma unroll
            for (int r = 0; r < 4; ++r) {
                float v = acc[mi][ni][r] + bv;
                if (WRITE_BF16)
                    ((__hip_bfloat16*)Cout)[(rowb + r) * (long)ldc + col] = __float2bfloat16(v);
                else
                    ((float*)Cout)[(rowb + r) * (long)ldc + col] = v;
            }
        }
    }
}

template <int WRITE_BF16>
__global__ __launch_bounds__(256)
void gemm_bias(const __hip_bfloat16* __restrict__ A0, int lda0,
               const __hip_bfloat16* __restrict__ A1, int lda1, int ksplit,
               const __hip_bfloat16* __restrict__ W, int ldw,
               const float* __restrict__ bias,
               void* __restrict__ Cout, int ldc, int K) {
    gemm_core<WRITE_BF16>(A0, lda0, A1, lda1, ksplit, W, ldw, bias, Cout, ldc, K,
                          blockIdx.x, blockIdx.y);
}

// Dual-problem GEMM: blockIdx.z selects problem. Parameters hoisted so only
// ONE gemm_core call site exists (one 32 KB LDS allocation, not two).
template <int WRITE_BF16>
__global__ __launch_bounds__(256)
void gemm_bias_dual(const __hip_bfloat16* A0a, int lda0a, const __hip_bfloat16* A1a,
                    int lda1a, int Ka, const __hip_bfloat16* Wa,
                    const float* biasa, void* Ca,
                    const __hip_bfloat16* A0b, int lda0b, const __hip_bfloat16* A1b,
                    int lda1b, int Kb, const __hip_bfloat16* Wb,
                    const float* biasb, void* Cb,
                    int ksplit, int ldw, int ldc) {
    const int z = blockIdx.z;
    const __hip_bfloat16* A0 = z ? A0b : A0a;
    const __hip_bfloat16* A1 = z ? A1b : A1a;
    const __hip_bfloat16* W  = z ? Wb  : Wa;
    const float* bias        = z ? biasb : biasa;
    void* Cout               = z ? Cb : Ca;
    int lda0 = z ? lda0b : lda0a;
    int lda1 = z ? lda1b : lda1a;
    int K    = z ? Kb : Ka;
    gemm_core<WRITE_BF16>(A0, lda0, A1, lda1, ksplit, W, ldw, bias, Cout, ldc, K,
                          blockIdx.x, blockIdx.y);
}

// ---------------------------------------------------------------------------
// Gate elementwise + the two LayerNorms. One block (256 thr) per batch row.
// g: [B, 2560] bf16 (f,i,o,cc,m blocks of 512). c: [B,512] f32 (updated).
// ---------------------------------------------------------------------------
__device__ __forceinline__ void block_reduce2(float& a, float& b, float* red) {
    #pragma unroll
    for (int off = 32; off > 0; off >>= 1) {
        a += __shfl_down(a, off, 64);
        b += __shfl_down(b, off, 64);
    }
    int lane = threadIdx.x & 63, w = threadIdx.x >> 6;
    if (lane == 0) { red[w] = a; red[8 + w] = b; }
    __syncthreads();
    a = red[0] + red[1] + red[2] + red[3];
    b = red[8] + red[9] + red[10] + red[11];
    __syncthreads();
}

__device__ __forceinline__
void gate_ew_body(const __hip_bfloat16* __restrict__ g, float* __restrict__ c,
                  const float* __restrict__ ret,
                  const float* __restrict__ elg, const float* __restrict__ elb,
                  const float* __restrict__ lng, const float* __restrict__ lnb,
                  __hip_bfloat16* __restrict__ hout, long hstride, int b) {
    const int tid = threadIdx.x;
    const __hip_bfloat16* gr = g + (long)b * NGATE_;
    __shared__ float red[16];

    float o_[2], cn_[2];
    float s = 0.f, s2 = 0.f;
    #pragma unroll
    for (int u = 0; u < 2; ++u) {
        int j = tid + u * 256;
        float fg = __bfloat162float(gr[j]);
        float ig = __bfloat162float(gr[512 + j]);
        float og = __bfloat162float(gr[1024 + j]);
        float cg = __bfloat162float(gr[1536 + j]);
        float mg = __bfloat162float(gr[2048 + j]);
        float f = sigmoidf_(fg), i = sigmoidf_(ig), o = sigmoidf_(og);
        float cc = tanhf(cg), m = sigmoidf_(mg);
        float cold = c[(long)b * H_ + j];
        float r = ret[j];
        float cn = f * cold + i * cc;
        cn = cn * r + (1.f - r) * cold;
        cn = m * cn + (1.f - m) * cold;
        c[(long)b * H_ + j] = cn;
        o_[u] = o; cn_[u] = cn;
        s += o; s2 += o * o;
    }
    block_reduce2(s, s2, red);
    float mean = s * (1.f / H_);
    float var = s2 * (1.f / H_) - mean * mean;
    float rstd = rsqrtf(var + EPSF);

    float val[2];
    float s3 = 0.f, s4 = 0.f;
    #pragma unroll
    for (int u = 0; u < 2; ++u) {
        int j = tid + u * 256;
        float on = (o_[u] - mean) * rstd * elg[j] + elb[j];
        float oe = sigmoidf_(on);
        float v = oe * tanhf(cn_[u]);
        val[u] = v; s3 += v; s4 += v * v;
    }
    block_reduce2(s3, s4, red);
    float mean2 = s3 * (1.f / H_);
    float var2 = s4 * (1.f / H_) - mean2 * mean2;
    float rstd2 = rsqrtf(var2 + EPSF);
    #pragma unroll
    for (int u = 0; u < 2; ++u) {
        int j = tid + u * 256;
        float h = (val[u] - mean2) * rstd2 * lng[j] + lnb[j];
        hout[(long)b * hstride + j] = __float2bfloat16(h);
    }
}

__global__ __launch_bounds__(256)
void gate_ew(const __hip_bfloat16* __restrict__ g, float* __restrict__ c,
             const float* __restrict__ ret,
             const float* __restrict__ elg, const float* __restrict__ elb,
             const float* __restrict__ lng, const float* __restrict__ lnb,
             __hip_bfloat16* __restrict__ hout, long hstride) {
    gate_ew_body(g, c, ret, elg, elb, lng, lnb, hout, hstride, blockIdx.x);
}

// Dual elementwise: blocks [0,B) run problem A, [B,2B) problem B.
__global__ __launch_bounds__(256)
void gate_ew_dual(const __hip_bfloat16* ga, float* ca, const float* reta,
                  const float* elga, const float* elba,
                  const float* lnga, const float* lnba,
                  __hip_bfloat16* houta, long hstridea,
                  const __hip_bfloat16* gb, float* cb, const float* retb,
                  const float* elgb, const float* elbb,
                  const float* lngb, const float* lnbb,
                  __hip_bfloat16* houtb, long hstrideb) {
    int bid = blockIdx.x;
    bool isB = bid >= B_;
    int b = isB ? bid - B_ : bid;
    const __hip_bfloat16* g = isB ? gb : ga;
    float* c        = isB ? cb : ca;
    const float* ret = isB ? retb : reta;
    const float* elg = isB ? elgb : elga;
    const float* elb = isB ? elbb : elba;
    const float* lng = isB ? lngb : lnga;
    const float* lnb = isB ? lnbb : lnba;
    __hip_bfloat16* hout = isB ? houtb : houta;
    long hstride = isB ? hstrideb : hstridea;
    gate_ew_body(g, c, ret, elg, elb, lng, lnb, hout, hstride, b);
}

// ---------------------------------------------------------------------------
// Attention for the last query only. One wave per (b, head), b chunk-local.
// kv: [KVCHUNK*30, 1024] bf16, cols 0..511 = k, 512..1023 = v.
// ---------------------------------------------------------------------------
__global__ __launch_bounds__(64)
void attn_kernel(const float* __restrict__ q, const __hip_bfloat16* __restrict__ kv,
                 __hip_bfloat16* __restrict__ outv) {
    const int bh = blockIdx.x;
    const int b = bh >> 2, h = bh & 3;
    const int l = threadIdx.x;
    const float scale = 0.0883883476483184f;  // 1/sqrt(128)
    float q0 = q[(long)b * H_ + h * DH_ + l];
    float q1 = q[(long)b * H_ + h * DH_ + 64 + l];
    __shared__ float p[32];
    for (int t = 0; t < TT; ++t) {
        const __hip_bfloat16* kp = kv + ((long)b * TT + t) * 1024 + h * DH_;
        float s = q0 * __bfloat162float(kp[l]) + q1 * __bfloat162float(kp[64 + l]);
        #pragma unroll
        for (int o = 32; o > 0; o >>= 1) s += __shfl_down(s, o, 64);
        if (l == 0) p[t] = s * scale;
    }
    __syncthreads();
    float mx = -1e30f;
    for (int t = 0; t < TT; ++t) mx = fmaxf(mx, p[t]);
    float den = 0.f;
    for (int t = 0; t < TT; ++t) den += __expf(p[t] - mx);
    float a0 = 0.f, a1 = 0.f;
    for (int t = 0; t < TT; ++t) {
        float wt = __expf(p[t] - mx);
        const __hip_bfloat16* vp = kv + ((long)b * TT + t) * 1024 + 512 + h * DH_;
        a0 += wt * __bfloat162float(vp[l]);
        a1 += wt * __bfloat162float(vp[64 + l]);
    }
    float inv = 1.f / den;
    outv[(long)b * H_ + h * DH_ + l] = __float2bfloat16(a0 * inv);
    outv[(long)b * H_ + h * DH_ + 64 + l] = __float2bfloat16(a1 * inv);
}

// ---------------------------------------------------------------------------
// Head: bn2 on latent then out (128->14). One block (128 thr) per batch row.
// latent read coalesced once; out_w (7 KB) L2-resident across blocks.
// ---------------------------------------------------------------------------
__global__ __launch_bounds__(128)
void head_kernel(const float* __restrict__ lat_in,
                 const float* __restrict__ g2, const float* __restrict__ b2,
                 const float* __restrict__ rm2, const float* __restrict__ rv2,
                 const float* __restrict__ ow, const float* __restrict__ ob,
                 float* __restrict__ out) {
    const int b = blockIdx.x, tid = threadIdx.x;
    __shared__ float ls[LAT_];
    float a = lat_in[(long)b * LAT_ + tid];
    ls[tid] = (a - rm2[tid]) * rsqrtf(rv2[tid] + EPSF) * g2[tid] + b2[tid];
    __syncthreads();
    if (tid < OUT_) {
        float acc = ob[tid];
        #pragma unroll 4
        for (int j = 0; j < LAT_; ++j) acc += ls[j] * ow[tid * LAT_ + j];
        out[(long)b * OUT_ + tid] = acc;
    }
}

// ---------------------------------------------------------------------------
extern "C" void kernel_launch(void* const* d_in, const int* in_sizes, int n_in,
                              void* d_out, int out_size, void* d_ws, size_t ws_size,
                              hipStream_t stream) {
    const float* x        = (const float*)d_in[0];
    const float* conv1_w  = (const float*)d_in[1];
    const float* conv1_b  = (const float*)d_in[2];
    const float* bn1_g    = (const float*)d_in[3];
    const float* bn1_b    = (const float*)d_in[4];
    const float* bn1_rm   = (const float*)d_in[5];
    const float* bn1_rv   = (const float*)d_in[6];
    const float* comp_w   = (const float*)d_in[7];
    const float* comp_b   = (const float*)d_in[8];
    const float* proj_w   = (const float*)d_in[9];
    const float* proj_b   = (const float*)d_in[10];
    const float* gates_w  = (const float*)d_in[11];
    const float* gates_b  = (const float*)d_in[12];
    const float* retention= (const float*)d_in[13];
    const float* expln_g  = (const float*)d_in[14];
    const float* expln_b  = (const float*)d_in[15];
    const float* ln_g     = (const float*)d_in[16];
    const float* ln_b     = (const float*)d_in[17];
    const float* attn_in_w  = (const float*)d_in[18];
    const float* attn_in_b  = (const float*)d_in[19];
    const float* attn_out_w = (const float*)d_in[20];
    const float* attn_out_b = (const float*)d_in[21];
    const float* bneck_w  = (const float*)d_in[22];
    const float* bneck_b  = (const float*)d_in[23];
    const float* bn2_g    = (const float*)d_in[24];
    const float* bn2_b    = (const float*)d_in[25];
    const float* bn2_rm   = (const float*)d_in[26];
    const float* bn2_rv   = (const float*)d_in[27];
    const float* out_w    = (const float*)d_in[28];
    const float* out_b    = (const float*)d_in[29];
    float* out = (float*)d_out;

    // ---- compact workspace layout (~218 MiB total) ----
    char* base = (char*)d_ws;
    size_t off = 0;
    auto alloc = [&](size_t nbytes) -> char* {
        char* p = base + off;
        off += (nbytes + 255) & ~(size_t)255;
        return p;
    };
    __hip_bfloat16* seq_bf = (__hip_bfloat16*)alloc((size_t)B_ * TT * H_ * 2);   // 126 MB
    // union: feat (front-end) / 2x bf16 gate buffers (scan) / kv chunk (attn)
    size_t g_bytes    = (size_t)B_ * NGATE_ * 2;                                 // 21 MB
    size_t kv_bytes   = (size_t)KVCHUNK * TT * 1024 * 2;                         // 31.4 MB
    size_t un_bytes   = 2 * g_bytes;                                             // 42 MB (max)
    char* un = alloc(un_bytes);
    __hip_bfloat16* feat_bf = (__hip_bfloat16*)un;
    __hip_bfloat16* gA_bf   = (__hip_bfloat16*)un;                 // layer-1 gates
    __hip_bfloat16* gB_bf   = (__hip_bfloat16*)(un + g_bytes);     // layer-0 gates
    __hip_bfloat16* kv_bf   = (__hip_bfloat16*)un;
    (void)kv_bytes;
    float*          c0    = (float*)alloc((size_t)B_ * H_ * 4);   // c0,c1 contiguous
    float*          c1    = (float*)alloc((size_t)B_ * H_ * 4);
    __hip_bfloat16* h0_bf = (__hip_bfloat16*)alloc((size_t)B_ * H_ * 2);
    float*          q_f   = (float*)alloc((size_t)B_ * H_ * 4);   // reused as fin_bf
    __hip_bfloat16* fin_bf = (__hip_bfloat16*)q_f;
    __hip_bfloat16* av_bf = (__hip_bfloat16*)alloc((size_t)B_ * H_ * 2);
    float*          lat_f = (float*)alloc((size_t)B_ * LAT_ * 4); // 2.1 MB
    __hip_bfloat16* gw_bf = (__hip_bfloat16*)alloc((size_t)L_ * 5 * H_ * 2 * H_ * 2);
    __hip_bfloat16* ai_bf = (__hip_bfloat16*)alloc((size_t)3 * H_ * H_ * 2);
    __hip_bfloat16* ao_bf = (__hip_bfloat16*)alloc((size_t)H_ * H_ * 2);
    __hip_bfloat16* pw_bf = (__hip_bfloat16*)alloc((size_t)H_ * FEATK * 2);
    __hip_bfloat16* bw_bf = (__hip_bfloat16*)alloc((size_t)LAT_ * H_ * 2);
    (void)ws_size; (void)in_sizes; (void)n_in; (void)out_size;

    // ---- weight conversion + state zeroing ----
    cvt_bf16<<<2048, 256, 0, stream>>>(gates_w, gw_bf, (long)L_ * 5 * H_ * 2 * H_);
    cvt_bf16<<<512, 256, 0, stream>>>(attn_in_w, ai_bf, (long)3 * H_ * H_);
    cvt_bf16<<<256, 256, 0, stream>>>(attn_out_w, ao_bf, (long)H_ * H_);
    cvt_bf16<<<64, 256, 0, stream>>>(bneck_w, bw_bf, (long)LAT_ * H_);
    pad_projw<<<(H_ * FEATK + 255) / 256, 256, 0, stream>>>(proj_w, pw_bf);
    zero_f32<<<2048, 256, 0, stream>>>(c0, (long)2 * B_ * H_);   // c0+c1 contiguous

    // ---- front-end: feat, then proj via MFMA GEMM ----
    frontend_kernel<<<B_, 256, 0, stream>>>(x, conv1_w, conv1_b, bn1_g, bn1_b, bn1_rm,
                                            bn1_rv, comp_w, comp_b, feat_bf);
    gemm_bias<1><<<dim3(H_ / 128, (B_ * TT) / 128), 256, 0, stream>>>(
        feat_bf, FEATK, (const __hip_bfloat16*)nullptr, 0, FEATK,
        pw_bf, FEATK, proj_b, (void*)seq_bf, H_, FEATK);

    // ---- recurrent scan (software-pipelined: layer1(t) || layer0(t+1)) ----
    const int WL = 5 * H_ * 2 * H_;  // weight elems per layer
    const dim3 ggrid(NGATE_ / 128, B_ / 128);
    const dim3 dgrid(NGATE_ / 128, B_ / 128, 2);

    // prologue: layer0 step 0 (h0==0 -> K=512 prefix)
    gemm_bias<1><<<ggrid, 256, 0, stream>>>(
        seq_bf, TT * H_, (const __hip_bfloat16*)nullptr, 0, H_,
        gw_bf, 2 * H_, gates_b, (void*)gB_bf, NGATE_, H_);
    gate_ew<<<B_, 256, 0, stream>>>(gB_bf, c0, retention, expln_g, expln_b,
                                    ln_g, ln_b, h0_bf, H_);

    for (int t = 0; t < TT - 1; ++t) {
        // problem A: layer1(t)  [t=0: h1 prev == 0 -> K=512 prefix]
        // problem B: layer0(t+1)
        gemm_bias_dual<1><<<dgrid, 256, 0, stream>>>(
            h0_bf, H_, (t == 0) ? (const __hip_bfloat16*)nullptr
                                : seq_bf + (size_t)(t - 1) * H_,
            TT * H_, (t == 0) ? H_ : 2 * H_, gw_bf + WL, gates_b + NGATE_, (void*)gA_bf,
            seq_bf + (size_t)(t + 1) * H_, TT * H_, h0_bf, H_, 2 * H_,
            gw_bf, gates_b, (void*)gB_bf,
            H_, 2 * H_, NGATE_);
        gate_ew_dual<<<2 * B_, 256, 0, stream>>>(
            gA_bf, c1, retention + H_, expln_g + H_, expln_b + H_,
            ln_g + H_, ln_b + H_, seq_bf + (size_t)t * H_, TT * H_,
            gB_bf, c0, retention, expln_g, expln_b,
            ln_g, ln_b, h0_bf, H_);
    }
    // epilogue: layer1 step 29
    gemm_bias<1><<<ggrid, 256, 0, stream>>>(
        h0_bf, H_, seq_bf + (size_t)(TT - 2) * H_, TT * H_, H_,
        gw_bf + WL, 2 * H_, gates_b + NGATE_, (void*)gA_bf, NGATE_, 2 * H_);
    gate_ew<<<B_, 256, 0, stream>>>(gA_bf, c1, retention + H_, expln_g + H_,
                                    expln_b + H_, ln_g + H_, ln_b + H_,
                                    seq_bf + (size_t)(TT - 1) * H_, TT * H_);

    // ---- q projection (last timestep only) ----
    gemm_bias<0><<<dim3(H_ / 128, B_ / 128), 256, 0, stream>>>(
        seq_bf + (size_t)29 * H_, TT * H_, (const __hip_bfloat16*)nullptr, 0, H_,
        ai_bf, H_, attn_in_b, (void*)q_f, H_, H_);

    // ---- kv projection + attention, in 8 batch chunks of KVCHUNK rows ----
    for (int bc = 0; bc < B_ / KVCHUNK; ++bc) {
        const __hip_bfloat16* seq_c = seq_bf + (size_t)bc * KVCHUNK * TT * H_;
        gemm_bias<1><<<dim3(1024 / 128, (KVCHUNK * TT) / 128), 256, 0, stream>>>(
            seq_c, H_, (const __hip_bfloat16*)nullptr, 0, H_,
            ai_bf + (size_t)H_ * H_, H_, attn_in_b + H_, (void*)kv_bf, 2 * H_, H_);
        attn_kernel<<<KVCHUNK * NH_, 64, 0, stream>>>(
            q_f + (size_t)bc * KVCHUNK * H_, kv_bf, av_bf + (size_t)bc * KVCHUNK * H_);
    }

    // ---- attn_out projection -> bf16 fin (aliases q_f; q fully consumed) ----
    gemm_bias<1><<<dim3(H_ / 128, B_ / 128), 256, 0, stream>>>(
        av_bf, H_, (const __hip_bfloat16*)nullptr, 0, H_,
        ao_bf, H_, attn_out_b, (void*)fin_bf, H_, H_);

    // ---- bneck via MFMA GEMM -> latent f32, then bn2+head ----
    gemm_bias<0><<<dim3(LAT_ / 128, B_ / 128), 256, 0, stream>>>(
        fin_bf, H_, (const __hip_bfloat16*)nullptr, 0, H_,
        bw_bf, H_, bneck_b, (void*)lat_f, LAT_, H_);
    head_kernel<<<B_, 128, 0, stream>>>(lat_f, bn2_g, bn2_b, bn2_rm, bn2_rv,
                                        out_w, out_b, out);
}

// Round 5
// 3242.200 us; speedup vs baseline: 1.3855x; 1.1044x over previous
//
#include <hip/hip_runtime.h>
#include <hip/hip_bf16.h>

// Problem constants
#define B_   4096
#define T_   60
#define TT   30          // pooled sequence length
#define H_   512
#define L_   2
#define NH_  4
#define DH_  128
#define LAT_ 128
#define OUT_ 14
#define NGATE_ (5*H_)    // 2560
#define EPSF 1e-5f
#define KVCHUNK 512      // batch rows per kv chunk (8 chunks)
#define FEATK 64         // feat padded to 64 (GEMM K granularity)

typedef __attribute__((ext_vector_type(8))) short bf16x8;
typedef __attribute__((ext_vector_type(4))) float f32x4;

__device__ __forceinline__ float sigmoidf_(float x) { return 1.0f / (1.0f + __expf(-x)); }

__device__ __forceinline__ void async_load16(const void* g, void* l) {
    __builtin_amdgcn_global_load_lds((const __attribute__((address_space(1))) void*)g,
                                     (__attribute__((address_space(3))) void*)l, 16, 0, 0);
}

// ---------------------------------------------------------------------------
// Utility kernels
// ---------------------------------------------------------------------------
__global__ __launch_bounds__(256) void cvt_bf16(const float* __restrict__ in,
                                                __hip_bfloat16* __restrict__ out, long n) {
    long i = (long)blockIdx.x * blockDim.x + threadIdx.x;
    long stride = (long)gridDim.x * blockDim.x;
    for (; i < n; i += stride) out[i] = __float2bfloat16(in[i]);
}

__global__ __launch_bounds__(256) void zero_f32(float* __restrict__ p, long n) {
    long i = (long)blockIdx.x * blockDim.x + threadIdx.x;
    long stride = (long)gridDim.x * blockDim.x;
    for (; i < n; i += stride) p[i] = 0.0f;
}

// proj_w [512,44] f32 -> padded [512,64] bf16 (cols 44..63 zero)
__global__ __launch_bounds__(256) void pad_projw(const float* __restrict__ pw,
                                                 __hip_bfloat16* __restrict__ out) {
    int i = blockIdx.x * 256 + threadIdx.x;      // 512*64 = 32768
    if (i >= H_ * FEATK) return;
    int r = i >> 6, c = i & 63;
    out[i] = __float2bfloat16(c < 44 ? pw[r * 44 + c] : 0.f);
}

// ---------------------------------------------------------------------------
// Front-end: conv1d(9->24,k3,p1)+relu+bn -> maxpool2 -> concat comp(8->20 relu)
// Writes feat [B*TT, 64] bf16 (cols 44..63 zero). Proj happens via MFMA GEMM.
// ---------------------------------------------------------------------------
__global__ __launch_bounds__(256)
void frontend_kernel(const float* __restrict__ x,
                     const float* __restrict__ cw, const float* __restrict__ cb,
                     const float* __restrict__ bg, const float* __restrict__ bb,
                     const float* __restrict__ brm, const float* __restrict__ brv,
                     const float* __restrict__ compw, const float* __restrict__ compb,
                     __hip_bfloat16* __restrict__ feat_out) {
    const int b = blockIdx.x, tid = threadIdx.x;
    __shared__ float xs[T_ * 17];        // 4080 B
    __shared__ float ybuf[24][T_];       // 5760 B
    __shared__ float feat[TT][44];       // 5280 B

    for (int i = tid; i < T_ * 17; i += 256) xs[i] = x[(long)b * T_ * 17 + i];
    __syncthreads();

    // conv + relu + bn1
    for (int i = tid; i < 24 * T_; i += 256) {
        int oc = i / T_, t = i % T_;
        float acc = cb[oc];
        #pragma unroll
        for (int kk = 0; kk < 3; ++kk) {
            int tt = t + kk - 1;
            if (tt >= 0 && tt < T_) {
                #pragma unroll
                for (int ic = 0; ic < 9; ++ic)
                    acc += xs[tt * 17 + ic] * cw[(oc * 9 + ic) * 3 + kk];
            }
        }
        acc = fmaxf(acc, 0.f);
        acc = (acc - brm[oc]) * rsqrtf(brv[oc] + EPSF) * bg[oc] + bb[oc];
        ybuf[oc][t] = acc;
    }
    __syncthreads();

    // maxpool(2) -> feat[:, :24]
    for (int i = tid; i < TT * 24; i += 256) {
        int u = i / 24, oc = i % 24;
        feat[u][oc] = fmaxf(ybuf[oc][2 * u], ybuf[oc][2 * u + 1]);
    }
    // comp: relu(x[:, :30, 9:17] @ comp_w.T + b) -> feat[:, 24:44]
    for (int i = tid; i < TT * 20; i += 256) {
        int u = i / 20, oc = i % 20;
        float acc = compb[oc];
        #pragma unroll
        for (int j = 0; j < 8; ++j) acc += xs[u * 17 + 9 + j] * compw[oc * 8 + j];
        feat[u][24 + oc] = fmaxf(acc, 0.f);
    }
    __syncthreads();

    // write padded bf16 feat rows
    for (int i = tid; i < TT * FEATK; i += 256) {
        int u = i >> 6, c = i & 63;
        float v = (c < 44) ? feat[u][c] : 0.f;
        feat_out[((long)b * TT + u) * FEATK + c] = __float2bfloat16(v);
    }
}

// ---------------------------------------------------------------------------
// bf16 MFMA GEMM core: C[m,n] = sum_k A[m,k] * W[n,k] + bias[n]
// A split along K at `ksplit` between A0 (stride lda0) and A1 (stride lda1).
// W has row stride ldw (>= K). 128x128 tile, BK=64, global_load_lds staging.
//
// LDS bank-conflict fix (R5): LDS slot (row, c) holds global K-chunk
// c ^ (row&7) (8-elem chunks within each 64-elem slab). global_load_lds's
// LDS dest is forced contiguous, but the global SOURCE is free per lane, so
// the permutation is applied there. Reads then hit 8 distinct bank-groups
// per 16-lane quarter (2-way aliasing = free, m136) instead of 16-way.
// ksplit stays slab-aligned (all uses are multiples of 64) so the A0/A1
// select is unaffected by the intra-slab permutation.
// ---------------------------------------------------------------------------
template <int WRITE_BF16>
__device__ __forceinline__
void gemm_core(const __hip_bfloat16* __restrict__ A0, int lda0,
               const __hip_bfloat16* __restrict__ A1, int lda1, int ksplit,
               const __hip_bfloat16* __restrict__ W, int ldw,
               const float* __restrict__ bias,
               void* __restrict__ Cout, int ldc, int K, int bx, int by) {
    __shared__ __hip_bfloat16 As[128 * 64];
    __shared__ __hip_bfloat16 Bs[128 * 64];
    const int tid = threadIdx.x;
    const int wave = tid >> 6, lane = tid & 63;
    const long m0 = (long)by * 128;
    const long n0 = (long)bx * 128;

    f32x4 acc[4][4] = {};

    for (int k0 = 0; k0 < K; k0 += 64) {
        __syncthreads();
        #pragma unroll
        for (int it = 0; it < 4; ++it) {
            int id = it * 256 + tid;          // 0..1023 -> 16 B each
            int row = id >> 3;                // 0..127
            int kc = ((id & 7) ^ (row & 7)) << 3;   // swizzled source chunk
            int gk = k0 + kc;
            const __hip_bfloat16* srcA;
            if (gk < ksplit) srcA = A0 + (m0 + row) * (long)lda0 + gk;
            else             srcA = A1 + (m0 + row) * (long)lda1 + (gk - ksplit);
            async_load16(srcA, &As[id * 8]);
            const __hip_bfloat16* srcB = W + (n0 + row) * (long)ldw + gk;
            async_load16(srcB, &Bs[id * 8]);
        }
        __syncthreads();
        #pragma unroll
        for (int ks = 0; ks < 2; ++ks) {
            // global chunk index c0 = ks*4 + (lane>>4); row&7 == lane&7 for
            // both ar and br -> same swizzled offset for A and B reads.
            const int kb = ((ks * 4 + (lane >> 4)) ^ (lane & 7)) << 3;
            const int ar = (wave >> 1) * 64 + (lane & 15);
            const int br = (wave & 1) * 64 + (lane & 15);
            bf16x8 afr[4], bfr[4];
            #pragma unroll
            for (int i = 0; i < 4; ++i) afr[i] = *(const bf16x8*)&As[(ar + i * 16) * 64 + kb];
            #pragma unroll
            for (int i = 0; i < 4; ++i) bfr[i] = *(const bf16x8*)&Bs[(br + i * 16) * 64 + kb];
            #pragma unroll
            for (int mi = 0; mi < 4; ++mi)
                #pragma unroll
                for (int ni = 0; ni < 4; ++ni)
                    acc[mi][ni] = __builtin_amdgcn_mfma_f32_16x16x32_bf16(afr[mi], bfr[ni], acc[mi][ni], 0, 0, 0);
        }
    }

    // epilogue: C/D layout col=lane&15, row=(lane>>4)*4+r
    const int cr = (lane >> 4) * 4;
    const int ccol = lane & 15;
    #pragma unroll
    for (int ni = 0; ni < 4; ++ni) {
        long col = n0 + (wave & 1) * 64 + ni * 16 + ccol;
        float bv = bias ? bias[col] : 0.f;
        #pragma unroll
        for (int mi = 0; mi < 4; ++mi) {
            long rowb = m0 + (wave >> 1) * 64 + mi * 16 + cr;
            #pragma unroll
            for (int r = 0; r < 4; ++r) {
                float v = acc[mi][ni][r] + bv;
                if (WRITE_BF16)
                    ((__hip_bfloat16*)Cout)[(rowb + r) * (long)ldc + col] = __float2bfloat16(v);
                else
                    ((float*)Cout)[(rowb + r) * (long)ldc + col] = v;
            }
        }
    }
}

template <int WRITE_BF16>
__global__ __launch_bounds__(256)
void gemm_bias(const __hip_bfloat16* __restrict__ A0, int lda0,
               const __hip_bfloat16* __restrict__ A1, int lda1, int ksplit,
               const __hip_bfloat16* __restrict__ W, int ldw,
               const float* __restrict__ bias,
               void* __restrict__ Cout, int ldc, int K) {
    gemm_core<WRITE_BF16>(A0, lda0, A1, lda1, ksplit, W, ldw, bias, Cout, ldc, K,
                          blockIdx.x, blockIdx.y);
}

// Dual-problem GEMM: blockIdx.z selects problem. Parameters hoisted so only
// ONE gemm_core call site exists (one 32 KB LDS allocation, not two).
template <int WRITE_BF16>
__global__ __launch_bounds__(256)
void gemm_bias_dual(const __hip_bfloat16* A0a, int lda0a, const __hip_bfloat16* A1a,
                    int lda1a, int Ka, const __hip_bfloat16* Wa,
                    const float* biasa, void* Ca,
                    const __hip_bfloat16* A0b, int lda0b, const __hip_bfloat16* A1b,
                    int lda1b, int Kb, const __hip_bfloat16* Wb,
                    const float* biasb, void* Cb,
                    int ksplit, int ldw, int ldc) {
    const int z = blockIdx.z;
    const __hip_bfloat16* A0 = z ? A0b : A0a;
    const __hip_bfloat16* A1 = z ? A1b : A1a;
    const __hip_bfloat16* W  = z ? Wb  : Wa;
    const float* bias        = z ? biasb : biasa;
    void* Cout               = z ? Cb : Ca;
    int lda0 = z ? lda0b : lda0a;
    int lda1 = z ? lda1b : lda1a;
    int K    = z ? Kb : Ka;
    gemm_core<WRITE_BF16>(A0, lda0, A1, lda1, ksplit, W, ldw, bias, Cout, ldc, K,
                          blockIdx.x, blockIdx.y);
}

// ---------------------------------------------------------------------------
// Gate elementwise + the two LayerNorms. One block (256 thr) per batch row.
// g: [B, 2560] bf16 (f,i,o,cc,m blocks of 512). c: [B,512] f32 (updated).
// ---------------------------------------------------------------------------
__device__ __forceinline__ void block_reduce2(float& a, float& b, float* red) {
    #pragma unroll
    for (int off = 32; off > 0; off >>= 1) {
        a += __shfl_down(a, off, 64);
        b += __shfl_down(b, off, 64);
    }
    int lane = threadIdx.x & 63, w = threadIdx.x >> 6;
    if (lane == 0) { red[w] = a; red[8 + w] = b; }
    __syncthreads();
    a = red[0] + red[1] + red[2] + red[3];
    b = red[8] + red[9] + red[10] + red[11];
    __syncthreads();
}

__device__ __forceinline__
void gate_ew_body(const __hip_bfloat16* __restrict__ g, float* __restrict__ c,
                  const float* __restrict__ ret,
                  const float* __restrict__ elg, const float* __restrict__ elb,
                  const float* __restrict__ lng, const float* __restrict__ lnb,
                  __hip_bfloat16* __restrict__ hout, long hstride, int b) {
    const int tid = threadIdx.x;
    const __hip_bfloat16* gr = g + (long)b * NGATE_;
    __shared__ float red[16];

    float o_[2], cn_[2];
    float s = 0.f, s2 = 0.f;
    #pragma unroll
    for (int u = 0; u < 2; ++u) {
        int j = tid + u * 256;
        float fg = __bfloat162float(gr[j]);
        float ig = __bfloat162float(gr[512 + j]);
        float og = __bfloat162float(gr[1024 + j]);
        float cg = __bfloat162float(gr[1536 + j]);
        float mg = __bfloat162float(gr[2048 + j]);
        float f = sigmoidf_(fg), i = sigmoidf_(ig), o = sigmoidf_(og);
        float cc = tanhf(cg), m = sigmoidf_(mg);
        float cold = c[(long)b * H_ + j];
        float r = ret[j];
        float cn = f * cold + i * cc;
        cn = cn * r + (1.f - r) * cold;
        cn = m * cn + (1.f - m) * cold;
        c[(long)b * H_ + j] = cn;
        o_[u] = o; cn_[u] = cn;
        s += o; s2 += o * o;
    }
    block_reduce2(s, s2, red);
    float mean = s * (1.f / H_);
    float var = s2 * (1.f / H_) - mean * mean;
    float rstd = rsqrtf(var + EPSF);

    float val[2];
    float s3 = 0.f, s4 = 0.f;
    #pragma unroll
    for (int u = 0; u < 2; ++u) {
        int j = tid + u * 256;
        float on = (o_[u] - mean) * rstd * elg[j] + elb[j];
        float oe = sigmoidf_(on);
        float v = oe * tanhf(cn_[u]);
        val[u] = v; s3 += v; s4 += v * v;
    }
    block_reduce2(s3, s4, red);
    float mean2 = s3 * (1.f / H_);
    float var2 = s4 * (1.f / H_) - mean2 * mean2;
    float rstd2 = rsqrtf(var2 + EPSF);
    #pragma unroll
    for (int u = 0; u < 2; ++u) {
        int j = tid + u * 256;
        float h = (val[u] - mean2) * rstd2 * lng[j] + lnb[j];
        hout[(long)b * hstride + j] = __float2bfloat16(h);
    }
}

__global__ __launch_bounds__(256)
void gate_ew(const __hip_bfloat16* __restrict__ g, float* __restrict__ c,
             const float* __restrict__ ret,
             const float* __restrict__ elg, const float* __restrict__ elb,
             const float* __restrict__ lng, const float* __restrict__ lnb,
             __hip_bfloat16* __restrict__ hout, long hstride) {
    gate_ew_body(g, c, ret, elg, elb, lng, lnb, hout, hstride, blockIdx.x);
}

// Dual elementwise: blocks [0,B) run problem A, [B,2B) problem B.
__global__ __launch_bounds__(256)
void gate_ew_dual(const __hip_bfloat16* ga, float* ca, const float* reta,
                  const float* elga, const float* elba,
                  const float* lnga, const float* lnba,
                  __hip_bfloat16* houta, long hstridea,
                  const __hip_bfloat16* gb, float* cb, const float* retb,
                  const float* elgb, const float* elbb,
                  const float* lngb, const float* lnbb,
                  __hip_bfloat16* houtb, long hstrideb) {
    int bid = blockIdx.x;
    bool isB = bid >= B_;
    int b = isB ? bid - B_ : bid;
    const __hip_bfloat16* g = isB ? gb : ga;
    float* c        = isB ? cb : ca;
    const float* ret = isB ? retb : reta;
    const float* elg = isB ? elgb : elga;
    const float* elb = isB ? elbb : elba;
    const float* lng = isB ? lngb : lnga;
    const float* lnb = isB ? lnbb : lnba;
    __hip_bfloat16* hout = isB ? houtb : houta;
    long hstride = isB ? hstrideb : hstridea;
    gate_ew_body(g, c, ret, elg, elb, lng, lnb, hout, hstride, b);
}

// ---------------------------------------------------------------------------
// Attention for the last query only. One wave per (b, head), b chunk-local.
// kv: [KVCHUNK*30, 1024] bf16, cols 0..511 = k, 512..1023 = v.
// ---------------------------------------------------------------------------
__global__ __launch_bounds__(64)
void attn_kernel(const float* __restrict__ q, const __hip_bfloat16* __restrict__ kv,
                 __hip_bfloat16* __restrict__ outv) {
    const int bh = blockIdx.x;
    const int b = bh >> 2, h = bh & 3;
    const int l = threadIdx.x;
    const float scale = 0.0883883476483184f;  // 1/sqrt(128)
    float q0 = q[(long)b * H_ + h * DH_ + l];
    float q1 = q[(long)b * H_ + h * DH_ + 64 + l];
    __shared__ float p[32];
    for (int t = 0; t < TT; ++t) {
        const __hip_bfloat16* kp = kv + ((long)b * TT + t) * 1024 + h * DH_;
        float s = q0 * __bfloat162float(kp[l]) + q1 * __bfloat162float(kp[64 + l]);
        #pragma unroll
        for (int o = 32; o > 0; o >>= 1) s += __shfl_down(s, o, 64);
        if (l == 0) p[t] = s * scale;
    }
    __syncthreads();
    float mx = -1e30f;
    for (int t = 0; t < TT; ++t) mx = fmaxf(mx, p[t]);
    float den = 0.f;
    for (int t = 0; t < TT; ++t) den += __expf(p[t] - mx);
    float a0 = 0.f, a1 = 0.f;
    for (int t = 0; t < TT; ++t) {
        float wt = __expf(p[t] - mx);
        const __hip_bfloat16* vp = kv + ((long)b * TT + t) * 1024 + 512 + h * DH_;
        a0 += wt * __bfloat162float(vp[l]);
        a1 += wt * __bfloat162float(vp[64 + l]);
    }
    float inv = 1.f / den;
    outv[(long)b * H_ + h * DH_ + l] = __float2bfloat16(a0 * inv);
    outv[(long)b * H_ + h * DH_ + 64 + l] = __float2bfloat16(a1 * inv);
}

// ---------------------------------------------------------------------------
// Head: bn2 on latent then out (128->14). One block (128 thr) per batch row.
// ---------------------------------------------------------------------------
__global__ __launch_bounds__(128)
void head_kernel(const float* __restrict__ lat_in,
                 const float* __restrict__ g2, const float* __restrict__ b2,
                 const float* __restrict__ rm2, const float* __restrict__ rv2,
                 const float* __restrict__ ow, const float* __restrict__ ob,
                 float* __restrict__ out) {
    const int b = blockIdx.x, tid = threadIdx.x;
    __shared__ float ls[LAT_];
    float a = lat_in[(long)b * LAT_ + tid];
    ls[tid] = (a - rm2[tid]) * rsqrtf(rv2[tid] + EPSF) * g2[tid] + b2[tid];
    __syncthreads();
    if (tid < OUT_) {
        float acc = ob[tid];
        #pragma unroll 4
        for (int j = 0; j < LAT_; ++j) acc += ls[j] * ow[tid * LAT_ + j];
        out[(long)b * OUT_ + tid] = acc;
    }
}

// ---------------------------------------------------------------------------
extern "C" void kernel_launch(void* const* d_in, const int* in_sizes, int n_in,
                              void* d_out, int out_size, void* d_ws, size_t ws_size,
                              hipStream_t stream) {
    const float* x        = (const float*)d_in[0];
    const float* conv1_w  = (const float*)d_in[1];
    const float* conv1_b  = (const float*)d_in[2];
    const float* bn1_g    = (const float*)d_in[3];
    const float* bn1_b    = (const float*)d_in[4];
    const float* bn1_rm   = (const float*)d_in[5];
    const float* bn1_rv   = (const float*)d_in[6];
    const float* comp_w   = (const float*)d_in[7];
    const float* comp_b   = (const float*)d_in[8];
    const float* proj_w   = (const float*)d_in[9];
    const float* proj_b   = (const float*)d_in[10];
    const float* gates_w  = (const float*)d_in[11];
    const float* gates_b  = (const float*)d_in[12];
    const float* retention= (const float*)d_in[13];
    const float* expln_g  = (const float*)d_in[14];
    const float* expln_b  = (const float*)d_in[15];
    const float* ln_g     = (const float*)d_in[16];
    const float* ln_b     = (const float*)d_in[17];
    const float* attn_in_w  = (const float*)d_in[18];
    const float* attn_in_b  = (const float*)d_in[19];
    const float* attn_out_w = (const float*)d_in[20];
    const float* attn_out_b = (const float*)d_in[21];
    const float* bneck_w  = (const float*)d_in[22];
    const float* bneck_b  = (const float*)d_in[23];
    const float* bn2_g    = (const float*)d_in[24];
    const float* bn2_b    = (const float*)d_in[25];
    const float* bn2_rm   = (const float*)d_in[26];
    const float* bn2_rv   = (const float*)d_in[27];
    const float* out_w    = (const float*)d_in[28];
    const float* out_b    = (const float*)d_in[29];
    float* out = (float*)d_out;

    // ---- compact workspace layout (~218 MiB total) ----
    char* base = (char*)d_ws;
    size_t off = 0;
    auto alloc = [&](size_t nbytes) -> char* {
        char* p = base + off;
        off += (nbytes + 255) & ~(size_t)255;
        return p;
    };
    __hip_bfloat16* seq_bf = (__hip_bfloat16*)alloc((size_t)B_ * TT * H_ * 2);   // 126 MB
    // union: feat (front-end) / 2x bf16 gate buffers (scan) / kv chunk (attn)
    size_t g_bytes    = (size_t)B_ * NGATE_ * 2;                                 // 21 MB
    size_t kv_bytes   = (size_t)KVCHUNK * TT * 1024 * 2;                         // 31.4 MB
    size_t un_bytes   = 2 * g_bytes;                                             // 42 MB (max)
    char* un = alloc(un_bytes);
    __hip_bfloat16* feat_bf = (__hip_bfloat16*)un;
    __hip_bfloat16* gA_bf   = (__hip_bfloat16*)un;                 // layer-1 gates
    __hip_bfloat16* gB_bf   = (__hip_bfloat16*)(un + g_bytes);     // layer-0 gates
    __hip_bfloat16* kv_bf   = (__hip_bfloat16*)un;
    (void)kv_bytes;
    float*          c0    = (float*)alloc((size_t)B_ * H_ * 4);   // c0,c1 contiguous
    float*          c1    = (float*)alloc((size_t)B_ * H_ * 4);
    __hip_bfloat16* h0_bf = (__hip_bfloat16*)alloc((size_t)B_ * H_ * 2);
    float*          q_f   = (float*)alloc((size_t)B_ * H_ * 4);   // reused as fin_bf
    __hip_bfloat16* fin_bf = (__hip_bfloat16*)q_f;
    __hip_bfloat16* av_bf = (__hip_bfloat16*)alloc((size_t)B_ * H_ * 2);
    float*          lat_f = (float*)alloc((size_t)B_ * LAT_ * 4); // 2.1 MB
    __hip_bfloat16* gw_bf = (__hip_bfloat16*)alloc((size_t)L_ * 5 * H_ * 2 * H_ * 2);
    __hip_bfloat16* ai_bf = (__hip_bfloat16*)alloc((size_t)3 * H_ * H_ * 2);
    __hip_bfloat16* ao_bf = (__hip_bfloat16*)alloc((size_t)H_ * H_ * 2);
    __hip_bfloat16* pw_bf = (__hip_bfloat16*)alloc((size_t)H_ * FEATK * 2);
    __hip_bfloat16* bw_bf = (__hip_bfloat16*)alloc((size_t)LAT_ * H_ * 2);
    (void)ws_size; (void)in_sizes; (void)n_in; (void)out_size;

    // ---- weight conversion + state zeroing ----
    cvt_bf16<<<2048, 256, 0, stream>>>(gates_w, gw_bf, (long)L_ * 5 * H_ * 2 * H_);
    cvt_bf16<<<512, 256, 0, stream>>>(attn_in_w, ai_bf, (long)3 * H_ * H_);
    cvt_bf16<<<256, 256, 0, stream>>>(attn_out_w, ao_bf, (long)H_ * H_);
    cvt_bf16<<<64, 256, 0, stream>>>(bneck_w, bw_bf, (long)LAT_ * H_);
    pad_projw<<<(H_ * FEATK + 255) / 256, 256, 0, stream>>>(proj_w, pw_bf);
    zero_f32<<<2048, 256, 0, stream>>>(c0, (long)2 * B_ * H_);   // c0+c1 contiguous

    // ---- front-end: feat, then proj via MFMA GEMM ----
    frontend_kernel<<<B_, 256, 0, stream>>>(x, conv1_w, conv1_b, bn1_g, bn1_b, bn1_rm,
                                            bn1_rv, comp_w, comp_b, feat_bf);
    gemm_bias<1><<<dim3(H_ / 128, (B_ * TT) / 128), 256, 0, stream>>>(
        feat_bf, FEATK, (const __hip_bfloat16*)nullptr, 0, FEATK,
        pw_bf, FEATK, proj_b, (void*)seq_bf, H_, FEATK);

    // ---- recurrent scan (software-pipelined: layer1(t) || layer0(t+1)) ----
    const int WL = 5 * H_ * 2 * H_;  // weight elems per layer
    const dim3 ggrid(NGATE_ / 128, B_ / 128);
    const dim3 dgrid(NGATE_ / 128, B_ / 128, 2);

    // prologue: layer0 step 0 (h0==0 -> K=512 prefix)
    gemm_bias<1><<<ggrid, 256, 0, stream>>>(
        seq_bf, TT * H_, (const __hip_bfloat16*)nullptr, 0, H_,
        gw_bf, 2 * H_, gates_b, (void*)gB_bf, NGATE_, H_);
    gate_ew<<<B_, 256, 0, stream>>>(gB_bf, c0, retention, expln_g, expln_b,
                                    ln_g, ln_b, h0_bf, H_);

    for (int t = 0; t < TT - 1; ++t) {
        // problem A: layer1(t)  [t=0: h1 prev == 0 -> K=512 prefix]
        // problem B: layer0(t+1)
        gemm_bias_dual<1><<<dgrid, 256, 0, stream>>>(
            h0_bf, H_, (t == 0) ? (const __hip_bfloat16*)nullptr
                                : seq_bf + (size_t)(t - 1) * H_,
            TT * H_, (t == 0) ? H_ : 2 * H_, gw_bf + WL, gates_b + NGATE_, (void*)gA_bf,
            seq_bf + (size_t)(t + 1) * H_, TT * H_, h0_bf, H_, 2 * H_,
            gw_bf, gates_b, (void*)gB_bf,
            H_, 2 * H_, NGATE_);
        gate_ew_dual<<<2 * B_, 256, 0, stream>>>(
            gA_bf, c1, retention + H_, expln_g + H_, expln_b + H_,
            ln_g + H_, ln_b + H_, seq_bf + (size_t)t * H_, TT * H_,
            gB_bf, c0, retention, expln_g, expln_b,
            ln_g, ln_b, h0_bf, H_);
    }
    // epilogue: layer1 step 29
    gemm_bias<1><<<ggrid, 256, 0, stream>>>(
        h0_bf, H_, seq_bf + (size_t)(TT - 2) * H_, TT * H_, H_,
        gw_bf + WL, 2 * H_, gates_b + NGATE_, (void*)gA_bf, NGATE_, 2 * H_);
    gate_ew<<<B_, 256, 0, stream>>>(gA_bf, c1, retention + H_, expln_g + H_,
                                    expln_b + H_, ln_g + H_, ln_b + H_,
                                    seq_bf + (size_t)(TT - 1) * H_, TT * H_);

    // ---- q projection (last timestep only) ----
    gemm_bias<0><<<dim3(H_ / 128, B_ / 128), 256, 0, stream>>>(
        seq_bf + (size_t)29 * H_, TT * H_, (const __hip_bfloat16*)nullptr, 0, H_,
        ai_bf, H_, attn_in_b, (void*)q_f, H_, H_);

    // ---- kv projection + attention, in 8 batch chunks of KVCHUNK rows ----
    for (int bc = 0; bc < B_ / KVCHUNK; ++bc) {
        const __hip_bfloat16* seq_c = seq_bf + (size_t)bc * KVCHUNK * TT * H_;
        gemm_bias<1><<<dim3(1024 / 128, (KVCHUNK * TT) / 128), 256, 0, stream>>>(
            seq_c, H_, (const __hip_bfloat16*)nullptr, 0, H_,
            ai_bf + (size_t)H_ * H_, H_, attn_in_b + H_, (void*)kv_bf, 2 * H_, H_);
        attn_kernel<<<KVCHUNK * NH_, 64, 0, stream>>>(
            q_f + (size_t)bc * KVCHUNK * H_, kv_bf, av_bf + (size_t)bc * KVCHUNK * H_);
    }

    // ---- attn_out projection -> bf16 fin (aliases q_f; q fully consumed) ----
    gemm_bias<1><<<dim3(H_ / 128, B_ / 128), 256, 0, stream>>>(
        av_bf, H_, (const __hip_bfloat16*)nullptr, 0, H_,
        ao_bf, H_, attn_out_b, (void*)fin_bf, H_, H_);

    // ---- bneck via MFMA GEMM -> latent f32, then bn2+head ----
    gemm_bias<0><<<dim3(LAT_ / 128, B_ / 128), 256, 0, stream>>>(
        fin_bf, H_, (const __hip_bfloat16*)nullptr, 0, H_,
        bw_bf, H_, bneck_b, (void*)lat_f, LAT_, H_);
    head_kernel<<<B_, 128, 0, stream>>>(lat_f, bn2_g, bn2_b, bn2_rm, bn2_rv,
                                        out_w, out_b, out);
}